// Round 2
// baseline (1186.198 us; speedup 1.0000x reference)
//
#include <hip/hip_runtime.h>
#include <hip/hip_bf16.h>
#include <cmath>

#define B_ 2
#define N_ 4096
#define E_ 1024
#define D_ 128
#define H_ 8
#define CHUNK 64
#define NC_ (N_/CHUNK)   // 64

__device__ __forceinline__ float sigmoidf_(float x){ return 1.f/(1.f + __expf(-x)); }

// ---------------------------------------------------------------------------
// Generic f32 GEMM: C[M,N] = A[M,K] @ Bw[N,K]^T   (both row-major, weights as
// given). Tiles BM x BN, K-step BK, per-thread micro-tile TM x TN composed of
// 4-wide float4 sub-blocks at offsets {0, BM/2} (when TM==8) for conflict-free
// LDS reads. 256 threads. All dims assumed divisible by tile sizes.
// ---------------------------------------------------------------------------
template<int BM,int BN,int BK,int TM,int TN>
__global__ __launch_bounds__(256) void gemm_f32(
    const float* __restrict__ A, const float* __restrict__ Bw,
    float* __restrict__ C, int M, int N, int K)
{
    constexpr int PAD  = 4;
    constexpr int LDA_ = BM + PAD;
    constexpr int LDB_ = BN + PAD;
    __shared__ float As[BK*LDA_];
    __shared__ float Bs[BK*LDB_];
    const int tid = threadIdx.x;
    const int tx = tid & 15, ty = tid >> 4;
    const int m0 = blockIdx.y * BM, n0 = blockIdx.x * BN;
    constexpr int SA = TM/4, SB = TN/4;
    constexpr int HA = BM / SA, HB = BN / SB;

    float acc[TM][TN];
#pragma unroll
    for (int i=0;i<TM;i++)
#pragma unroll
        for (int j=0;j<TN;j++) acc[i][j]=0.f;

    constexpr int NKQ = BK/4;           // float4 quads per row of the k-slab
    const int lm = tid / NKQ;           // loader row (BM*NKQ == 256 assumed)
    const int lk = (tid % NKQ)*4;       // loader k offset

    for (int k0=0;k0<K;k0+=BK){
        const float4 av = *reinterpret_cast<const float4*>(&A [(size_t)(m0+lm)*K + k0 + lk]);
        const float4 bv = *reinterpret_cast<const float4*>(&Bw[(size_t)(n0+lm)*K + k0 + lk]);
        __syncthreads();   // previous iteration's reads must finish before overwrite
        As[(lk+0)*LDA_ + lm]=av.x; As[(lk+1)*LDA_ + lm]=av.y;
        As[(lk+2)*LDA_ + lm]=av.z; As[(lk+3)*LDA_ + lm]=av.w;
        Bs[(lk+0)*LDB_ + lm]=bv.x; Bs[(lk+1)*LDB_ + lm]=bv.y;
        Bs[(lk+2)*LDB_ + lm]=bv.z; Bs[(lk+3)*LDB_ + lm]=bv.w;
        __syncthreads();
#pragma unroll
        for (int kk=0;kk<BK;kk++){
            float a[TM], b[TN];
#pragma unroll
            for (int s=0;s<SA;s++){
                const float4 t4 = *reinterpret_cast<const float4*>(&As[kk*LDA_ + s*HA + 4*ty]);
                a[s*4+0]=t4.x; a[s*4+1]=t4.y; a[s*4+2]=t4.z; a[s*4+3]=t4.w;
            }
#pragma unroll
            for (int s=0;s<SB;s++){
                const float4 t4 = *reinterpret_cast<const float4*>(&Bs[kk*LDB_ + s*HB + 4*tx]);
                b[s*4+0]=t4.x; b[s*4+1]=t4.y; b[s*4+2]=t4.z; b[s*4+3]=t4.w;
            }
#pragma unroll
            for (int i=0;i<TM;i++)
#pragma unroll
                for (int j=0;j<TN;j++)
                    acc[i][j] = fmaf(a[i], b[j], acc[i][j]);
        }
    }
#pragma unroll
    for (int si=0; si<SA; si++)
#pragma unroll
        for (int r=0;r<4;r++){
            const int m = m0 + si*HA + 4*ty + r;
#pragma unroll
            for (int sj=0; sj<SB; sj++){
                float4 o;
                o.x=acc[si*4+r][sj*4+0]; o.y=acc[si*4+r][sj*4+1];
                o.z=acc[si*4+r][sj*4+2]; o.w=acc[si*4+r][sj*4+3];
                *reinterpret_cast<float4*>(&C[(size_t)m*N + n0 + sj*HB + 4*tx]) = o;
            }
        }
}

// ---------------------------------------------------------------------------
// Prep (IN PLACE inside u): per (b,h,chunk), per d-column: sequential prefix
// over t of g = logsigmoid(lg). Overwrites the q slot with
// QS = silu(q)*exp(b) and the lg slot with KIN = (1-sigmoid(lg))*exp(-b).
// Emits BC = b at chunk end. Each thread touches only its own elements.
// ---------------------------------------------------------------------------
__global__ __launch_bounds__(128) void gla_prep(
    float* __restrict__ u, float* __restrict__ BC)
{
    const int bid = blockIdx.x;               // (b*H + h)*NC + c
    const int c = bid % NC_;
    const int h = (bid / NC_) % H_;
    const int b = bid / (NC_*H_);
    const int d = threadIdx.x;                // 0..127
    const size_t urow0 = ((size_t)b*N_ + (size_t)c*CHUNK)*(3*E_) + (size_t)h*D_ + d;
    float bacc = 0.f;
    for (int t=0;t<CHUNK;t++){
        const size_t r = urow0 + (size_t)t*(3*E_);
        const float q  = u[r + E_];
        const float lg = u[r + 2*E_];
        const float sq = q * sigmoidf_(q);                           // silu
        const float g  = (lg >= 0.f) ? -log1pf(__expf(-lg))
                                     : (lg - log1pf(__expf(lg)));    // logsigmoid
        const float kk = sigmoidf_(-lg);                             // 1 - sigmoid(lg)
        bacc += g;
        u[r + E_]   = sq * __expf(bacc);      // QS
        u[r + 2*E_] = kk * __expf(-bacc);     // KIN
    }
    BC[(size_t)bid*D_ + d] = bacc;
}

// ---------------------------------------------------------------------------
// Chunk summary: Mc[d,e] = exp(BC[d]) * sum_s KIN[s,d] * V[s,e]
// KIN = u's lg slot, V = u's v slot. One block per (b,h,chunk).
// ---------------------------------------------------------------------------
__global__ __launch_bounds__(256) void gla_chunk_sum(
    const float* __restrict__ u, const float* __restrict__ BC,
    float* __restrict__ Mc)
{
    __shared__ float kin_l[CHUNK*132];
    __shared__ float v_l[CHUNK*132];
    const int bid = blockIdx.x;
    const int c = bid % NC_;
    const int h = (bid / NC_) % H_;
    const int b = bid / (NC_*H_);
    const int tid = threadIdx.x;
    const int tx = tid & 15, ty = tid >> 4;
    const size_t urow0 = ((size_t)b*N_ + (size_t)c*CHUNK)*(3*E_) + (size_t)h*D_;
#pragma unroll
    for (int f = tid; f < CHUNK*32; f += 256){
        const int s = f >> 5, dq = (f & 31)*4;
        const float4 kv = *reinterpret_cast<const float4*>(&u[urow0 + 2*E_ + (size_t)s*(3*E_) + dq]);
        const float4 vv = *reinterpret_cast<const float4*>(&u[urow0 +        (size_t)s*(3*E_) + dq]);
        kin_l[s*132+dq+0]=kv.x; kin_l[s*132+dq+1]=kv.y; kin_l[s*132+dq+2]=kv.z; kin_l[s*132+dq+3]=kv.w;
        v_l  [s*132+dq+0]=vv.x; v_l  [s*132+dq+1]=vv.y; v_l  [s*132+dq+2]=vv.z; v_l  [s*132+dq+3]=vv.w;
    }
    __syncthreads();
    float acc[8][8];
#pragma unroll
    for (int i=0;i<8;i++)
#pragma unroll
        for (int j=0;j<8;j++) acc[i][j]=0.f;
    for (int s=0;s<CHUNK;s++){
        const float4 a0 = *reinterpret_cast<const float4*>(&kin_l[s*132 + 4*ty]);
        const float4 a1 = *reinterpret_cast<const float4*>(&kin_l[s*132 + 64 + 4*ty]);
        const float4 b0 = *reinterpret_cast<const float4*>(&v_l[s*132 + 4*tx]);
        const float4 b1 = *reinterpret_cast<const float4*>(&v_l[s*132 + 64 + 4*tx]);
        const float a[8]  = {a0.x,a0.y,a0.z,a0.w,a1.x,a1.y,a1.z,a1.w};
        const float bb[8] = {b0.x,b0.y,b0.z,b0.w,b1.x,b1.y,b1.z,b1.w};
#pragma unroll
        for (int i=0;i<8;i++)
#pragma unroll
            for (int j=0;j<8;j++)
                acc[i][j] = fmaf(a[i], bb[j], acc[i][j]);
    }
#pragma unroll
    for (int i=0;i<8;i++){
        const int dI = (i<4) ? (4*ty+i) : (64 + 4*ty + (i-4));
        const float dec = __expf(BC[(size_t)bid*D_ + dI]);
        float4 o0, o1;
        o0.x=acc[i][0]*dec; o0.y=acc[i][1]*dec; o0.z=acc[i][2]*dec; o0.w=acc[i][3]*dec;
        o1.x=acc[i][4]*dec; o1.y=acc[i][5]*dec; o1.z=acc[i][6]*dec; o1.w=acc[i][7]*dec;
        float* mp = &Mc[(size_t)bid*D_*D_ + (size_t)dI*D_];
        *reinterpret_cast<float4*>(&mp[4*tx])      = o0;
        *reinterpret_cast<float4*>(&mp[64 + 4*tx]) = o1;
    }
}

// ---------------------------------------------------------------------------
// Inter-chunk scan, in place: each thread owns one (b,h,d,e) element.
// After this, McS[c] holds the state at the START of chunk c.
// ---------------------------------------------------------------------------
__global__ __launch_bounds__(256) void gla_scan_chunks(
    float* __restrict__ McS, const float* __restrict__ BC)
{
    const size_t F = (size_t)blockIdx.x*256 + threadIdx.x;   // < B*H*D*D
    const int bh = (int)(F >> 14);
    const int rem = (int)(F & 16383);
    const int d = rem >> 7;
    float Scur = 0.f;
    for (int c=0;c<NC_;c++){
        const size_t idx = (((size_t)bh*NC_ + c) << 14) + rem;
        const float m = McS[idx];
        const float dec = __expf(BC[((size_t)bh*NC_ + c)*D_ + d]);
        McS[idx] = Scur;
        Scur = dec*Scur + m;
    }
}

// ---------------------------------------------------------------------------
// Output: per (b,h,chunk): A = causal_mask(QS @ KIN^T); O = A@V + QS@S_start.
// QS/KIN/V all live inside u (slots q/lg/v). Writes [B,N,E] layout.
// ---------------------------------------------------------------------------
__global__ __launch_bounds__(256) void gla_output(
    const float* __restrict__ u, const float* __restrict__ S,
    float* __restrict__ Opre)
{
    __shared__ float qs_l[CHUNK*132];
    __shared__ float kv_l[CHUNK*132];    // KIN, then V
    __shared__ float a_l[CHUNK*68];      // A matrix; reused as S tile [16][132]
    const int bid = blockIdx.x;
    const int c = bid % NC_;
    const int h = (bid / NC_) % H_;
    const int b = bid / (NC_*H_);
    const int tid = threadIdx.x;
    const int tx = tid & 15, ty = tid >> 4;
    const size_t urow0 = ((size_t)b*N_ + (size_t)c*CHUNK)*(3*E_) + (size_t)h*D_;
#pragma unroll
    for (int f = tid; f < CHUNK*32; f += 256){
        const int s = f >> 5, dq = (f & 31)*4;
        const float4 qv = *reinterpret_cast<const float4*>(&u[urow0 +   E_ + (size_t)s*(3*E_) + dq]);
        const float4 kv = *reinterpret_cast<const float4*>(&u[urow0 + 2*E_ + (size_t)s*(3*E_) + dq]);
        qs_l[s*132+dq+0]=qv.x; qs_l[s*132+dq+1]=qv.y; qs_l[s*132+dq+2]=qv.z; qs_l[s*132+dq+3]=qv.w;
        kv_l[s*132+dq+0]=kv.x; kv_l[s*132+dq+1]=kv.y; kv_l[s*132+dq+2]=kv.z; kv_l[s*132+dq+3]=kv.w;
    }
    __syncthreads();
    // phase 2: A[t][s] = sum_d QS[t,d]*KIN[s,d]
    float pa[4][4];
#pragma unroll
    for (int i=0;i<4;i++)
#pragma unroll
        for (int j=0;j<4;j++) pa[i][j]=0.f;
    for (int d=0; d<D_; d++){
        float a[4], bb[4];
#pragma unroll
        for (int i=0;i<4;i++) a[i]  = qs_l[(4*ty+i)*132 + d];
#pragma unroll
        for (int j=0;j<4;j++) bb[j] = kv_l[(4*tx+j)*132 + d];
#pragma unroll
        for (int i=0;i<4;i++)
#pragma unroll
            for (int j=0;j<4;j++)
                pa[i][j] = fmaf(a[i], bb[j], pa[i][j]);
    }
    __syncthreads();   // all reads of kv_l done before overwrite with V
    // write masked A; load V over KIN
#pragma unroll
    for (int i=0;i<4;i++)
#pragma unroll
        for (int j=0;j<4;j++){
            const int t = 4*ty+i, s = 4*tx+j;
            a_l[t*68 + s] = (t >= s) ? pa[i][j] : 0.f;
        }
#pragma unroll
    for (int f = tid; f < CHUNK*32; f += 256){
        const int s = f >> 5, dq = (f & 31)*4;
        const float4 vv = *reinterpret_cast<const float4*>(&u[urow0 + (size_t)s*(3*E_) + dq]);
        kv_l[s*132+dq+0]=vv.x; kv_l[s*132+dq+1]=vv.y; kv_l[s*132+dq+2]=vv.z; kv_l[s*132+dq+3]=vv.w;
    }
    __syncthreads();
    // phase 3: O = A @ V
    float o[4][8];
#pragma unroll
    for (int i=0;i<4;i++)
#pragma unroll
        for (int j=0;j<8;j++) o[i][j]=0.f;
    for (int s=0;s<CHUNK;s++){
        float a[4];
#pragma unroll
        for (int i=0;i<4;i++) a[i] = a_l[(4*ty+i)*68 + s];
        const float4 v0 = *reinterpret_cast<const float4*>(&kv_l[s*132 + 4*tx]);
        const float4 v1 = *reinterpret_cast<const float4*>(&kv_l[s*132 + 64 + 4*tx]);
        const float vv[8] = {v0.x,v0.y,v0.z,v0.w,v1.x,v1.y,v1.z,v1.w};
#pragma unroll
        for (int i=0;i<4;i++)
#pragma unroll
            for (int j=0;j<8;j++)
                o[i][j] = fmaf(a[i], vv[j], o[i][j]);
    }
    // phase 4: O += QS @ S_start   (stream S through LDS in 16-row slabs)
    const float* Sb = &S[(size_t)bid*D_*D_];
    for (int d0=0; d0<D_; d0+=16){
        __syncthreads();
#pragma unroll
        for (int f=tid; f<16*32; f+=256){
            const int dr = f >> 5, dq = (f & 31)*4;
            const float4 sv = *reinterpret_cast<const float4*>(&Sb[(size_t)(d0+dr)*D_ + dq]);
            a_l[dr*132+dq+0]=sv.x; a_l[dr*132+dq+1]=sv.y; a_l[dr*132+dq+2]=sv.z; a_l[dr*132+dq+3]=sv.w;
        }
        __syncthreads();
#pragma unroll
        for (int dd=0; dd<16; dd++){
            float a[4];
#pragma unroll
            for (int i=0;i<4;i++) a[i] = qs_l[(4*ty+i)*132 + d0+dd];
            const float4 s0 = *reinterpret_cast<const float4*>(&a_l[dd*132 + 4*tx]);
            const float4 s1 = *reinterpret_cast<const float4*>(&a_l[dd*132 + 64 + 4*tx]);
            const float ss[8] = {s0.x,s0.y,s0.z,s0.w,s1.x,s1.y,s1.z,s1.w};
#pragma unroll
            for (int i=0;i<4;i++)
#pragma unroll
                for (int j=0;j<8;j++)
                    o[i][j] = fmaf(a[i], ss[j], o[i][j]);
        }
    }
    // store into [B,N,E]
#pragma unroll
    for (int i=0;i<4;i++){
        const int t = 4*ty + i;
        const size_t orow = ((size_t)b*N_ + (size_t)c*CHUNK + t)*E_ + (size_t)h*D_;
        float4 o0, o1;
        o0.x=o[i][0]; o0.y=o[i][1]; o0.z=o[i][2]; o0.w=o[i][3];
        o1.x=o[i][4]; o1.y=o[i][5]; o1.z=o[i][6]; o1.w=o[i][7];
        *reinterpret_cast<float4*>(&Opre[orow + 4*tx])      = o0;
        *reinterpret_cast<float4*>(&Opre[orow + 64 + 4*tx]) = o1;
    }
}

// ---------------------------------------------------------------------------
// Gate (sigmoid of low-rank proj) + LayerNorm, in place on O.
// One block per row of E=1024; 256 threads x float4.
// ---------------------------------------------------------------------------
__global__ __launch_bounds__(256) void gate_ln(
    float* __restrict__ O, const float* __restrict__ G2,
    const float* __restrict__ lnw)
{
    const int row = blockIdx.x;
    const int tid = threadIdx.x;
    const size_t off = (size_t)row*E_ + tid*4;
    float4 o = *reinterpret_cast<const float4*>(&O[off]);
    const float4 g = *reinterpret_cast<const float4*>(&G2[off]);
    o.x *= sigmoidf_(g.x); o.y *= sigmoidf_(g.y);
    o.z *= sigmoidf_(g.z); o.w *= sigmoidf_(g.w);
    float s1 = o.x+o.y+o.z+o.w;
    float s2 = o.x*o.x + o.y*o.y + o.z*o.z + o.w*o.w;
#pragma unroll
    for (int sh=32; sh>0; sh>>=1){
        s1 += __shfl_down(s1, sh);
        s2 += __shfl_down(s2, sh);
    }
    __shared__ float r1[4], r2[4];
    const int wid = tid >> 6;
    if ((tid & 63)==0){ r1[wid]=s1; r2[wid]=s2; }
    __syncthreads();
    s1 = r1[0]+r1[1]+r1[2]+r1[3];
    s2 = r2[0]+r2[1]+r2[2]+r2[3];
    const float mean = s1 * (1.f/E_);
    const float var  = s2 * (1.f/E_) - mean*mean;
    const float rs   = rsqrtf(var + 1e-5f);
    const float4 w = *reinterpret_cast<const float4*>(&lnw[tid*4]);
    float4 r;
    r.x = (o.x-mean)*rs*w.x; r.y = (o.y-mean)*rs*w.y;
    r.z = (o.z-mean)*rs*w.z; r.w = (o.w-mean)*rs*w.w;
    *reinterpret_cast<float4*>(&O[off]) = r;
}

// ---------------------------------------------------------------------------
extern "C" void kernel_launch(void* const* d_in, const int* in_sizes, int n_in,
                              void* d_out, int out_size, void* d_ws, size_t ws_size,
                              hipStream_t stream)
{
    const float* x     = (const float*)d_in[0];
    const float* W_in  = (const float*)d_in[1];
    const float* W_out = (const float*)d_in[2];
    const float* W_g1  = (const float*)d_in[3];
    const float* W_g2  = (const float*)d_in[4];
    const float* lnw   = (const float*)d_in[5];
    float* out = (float*)d_out;
    char* ws = (char*)d_ws;

    // workspace layout (bytes); total 206,045,184  (< 256 MiB)
    float* u    = (float*)(ws);                 // [B,N,3E]    100,663,296 B
    float* BC   = (float*)(ws + 100663296);     // [B,H,NC,D]      524,288 B
    float* Mc   = (float*)(ws + 101187584);     // [B,H,NC,D,D] 67,108,864 B (becomes S states)
    float* Opre = (float*)(ws + 168296448);     // [B,N,E]      33,554,432 B
    float* G1   = (float*)(ws + 201850880);     // [B*N,D]       4,194,304 B
    float* G2   = u;                            // reuse u after gla_output

    const int M = B_*N_;     // 8192
    dim3 blk(256);

    // 1) u = x @ W_in^T    [8192,1024]x[3072,1024]^T
    gemm_f32<128,128,8,8,8><<<dim3(3*E_/128, M/128), blk, 0, stream>>>(x, W_in, u, M, 3*E_, E_);
    // 2) decay-scaled q,k + chunk prefix sums (in place in u)
    gla_prep<<<dim3(B_*H_*NC_), dim3(128), 0, stream>>>(u, BC);
    // 3) per-chunk summaries Mc
    gla_chunk_sum<<<dim3(B_*H_*NC_), blk, 0, stream>>>(u, BC, Mc);
    // 4) inter-chunk scan (in place; Mc -> chunk-start states)
    gla_scan_chunks<<<dim3((B_*H_*D_*D_)/256), blk, 0, stream>>>(Mc, BC);
    // 5) per-chunk outputs
    gla_output<<<dim3(B_*H_*NC_), blk, 0, stream>>>(u, Mc, Opre);
    // 6) G1 = x @ W_g1^T   [8192,1024]x[128,1024]^T
    gemm_f32<64,64,16,4,4><<<dim3(D_/64, M/64), blk, 0, stream>>>(x, W_g1, G1, M, D_, E_);
    // 7) G2 = G1 @ W_g2^T  [8192,128]x[1024,128]^T  (into u, now dead)
    gemm_f32<128,128,8,8,8><<<dim3(E_/128, M/128), blk, 0, stream>>>(G1, W_g2, G2, M, E_, D_);
    // 8) gate + layernorm in place on Opre
    gate_ln<<<dim3(M), blk, 0, stream>>>(Opre, G2, lnw);
    // 9) out = Opre @ W_out^T
    gemm_f32<128,128,8,8,8><<<dim3(E_/128, M/128), blk, 0, stream>>>(Opre, W_out, out, M, E_, E_);
}

// Round 3
// 439.600 us; speedup vs baseline: 2.6984x; 2.6984x over previous
//
#include <hip/hip_runtime.h>
#include <cmath>

#define B_ 2
#define N_ 4096
#define E_ 1024
#define D_ 128
#define H_ 8
#define CHUNK 64
#define NC_ (N_/CHUNK)   // 64

__device__ __forceinline__ float sigmoidf_(float x){ return 1.f/(1.f + __expf(-x)); }

__device__ __forceinline__ unsigned short f2bf(float f){
    unsigned u = __float_as_uint(f);
    u += 0x7FFFu + ((u >> 16) & 1u);      // round-to-nearest-even
    return (unsigned short)(u >> 16);
}

typedef __attribute__((ext_vector_type(8))) __bf16 bf16x8;
typedef __attribute__((ext_vector_type(4))) float  f32x4;
typedef __attribute__((address_space(3))) unsigned int as3_u32;
typedef __attribute__((address_space(1))) unsigned int as1_u32;

__device__ __forceinline__ void gload_lds16(const void* g, void* l){
    __builtin_amdgcn_global_load_lds((as1_u32*)g, (as3_u32*)l, 16, 0, 0);
}

// ---------------------------------------------------------------------------
// bf16 MFMA GEMM: C[M,N] = A[M,K] @ Bw[N,K]^T. A,Bw bf16 row-major; C f32 or
// bf16. 128x128 tile, BK=64, 4 waves (2x2 of 64x64), 16x16x32 MFMA.
// Staging: global_load_lds dwordx4, LDS linear [128][64] bf16 (128B rows),
// XOR swizzle (16B group ^= row&7) applied on the global SOURCE address and
// again on the ds_read address (both-sides involution, rule #21).
// Requires M%128==0, N%128==0, K%64==0.
// ---------------------------------------------------------------------------
template<bool OUT_BF16>
__global__ __launch_bounds__(256) void gemm_bf16(
    const unsigned short* __restrict__ A,
    const unsigned short* __restrict__ Bw,
    void* __restrict__ Cout, int M, int N, int K)
{
    __shared__ unsigned short As[128*64];
    __shared__ unsigned short Bs[128*64];
    const int tid  = threadIdx.x;
    const int wave = tid >> 6;
    const int lane = tid & 63;
    const int m0 = blockIdx.y * 128, n0 = blockIdx.x * 128;
    const int wr = (wave >> 1) * 64;      // wave row offset in tile
    const int wc = (wave & 1) * 64;       // wave col offset
    const int l15 = lane & 15, l4 = lane >> 4;
    const int p = l15 & 7;                // row&7 of every fragment row this lane reads

    f32x4 acc[4][4];
#pragma unroll
    for (int i=0;i<4;i++)
#pragma unroll
        for (int j=0;j<4;j++)
#pragma unroll
            for (int q=0;q<4;q++) acc[i][j][q]=0.f;

    const int srow = wave*32 + (lane>>3);   // staging row (+8*i)
    const int sgrp = lane & 7;              // staging 16B-group within 128B row

    for (int k0=0; k0<K; k0+=64){
        if (k0) __syncthreads();            // protect LDS from prior reads
#pragma unroll
        for (int i=0;i<4;i++){
            const int r  = srow + 8*i;
            const int cg = sgrp ^ (r & 7);  // inverse-swizzled source col-group
            gload_lds16(A  + (size_t)(m0 + r)*K + k0 + cg*8, &As[(wave*32 + 8*i)*64]);
            gload_lds16(Bw + (size_t)(n0 + r)*K + k0 + cg*8, &Bs[(wave*32 + 8*i)*64]);
        }
        __syncthreads();                    // drains vmcnt (compiler-inserted)
#pragma unroll
        for (int ks=0; ks<2; ks++){
            bf16x8 av[4], bv[4];
            const int tA = (((ks<<2) | l4) ^ p) << 3;   // swizzled 16B group -> ushort idx
#pragma unroll
            for (int f=0; f<4; f++){
                const int rowA = wr + f*16 + l15;
                const int rowB = wc + f*16 + l15;
                av[f] = *reinterpret_cast<const bf16x8*>(&As[(rowA<<6) + tA]);
                bv[f] = *reinterpret_cast<const bf16x8*>(&Bs[(rowB<<6) + tA]);
            }
#pragma unroll
            for (int fm=0; fm<4; fm++)
#pragma unroll
                for (int fn=0; fn<4; fn++)
                    acc[fm][fn] = __builtin_amdgcn_mfma_f32_16x16x32_bf16(
                        av[fm], bv[fn], acc[fm][fn], 0, 0, 0);
        }
    }
    // C/D layout: col = lane&15, row = (lane>>4)*4 + reg  [m89 verified]
    const int crow0 = m0 + wr + l4*4;
    const int ccol0 = n0 + wc + l15;
    if (!OUT_BF16){
        float* C = (float*)Cout;
#pragma unroll
        for (int fm=0; fm<4; fm++)
#pragma unroll
            for (int fn=0; fn<4; fn++)
#pragma unroll
                for (int j=0;j<4;j++)
                    C[(size_t)(crow0 + fm*16 + j)*N + ccol0 + fn*16] = acc[fm][fn][j];
    } else {
        unsigned short* C = (unsigned short*)Cout;
#pragma unroll
        for (int fm=0; fm<4; fm++)
#pragma unroll
            for (int fn=0; fn<4; fn++)
#pragma unroll
                for (int j=0;j<4;j++)
                    C[(size_t)(crow0 + fm*16 + j)*N + ccol0 + fn*16] = f2bf(acc[fm][fn][j]);
    }
}

// ---------------------------------------------------------------------------
// f32 -> bf16 cast, float4 per thread, grid-stride.
// ---------------------------------------------------------------------------
__global__ __launch_bounds__(256) void cast_bf16(
    const float* __restrict__ in, unsigned short* __restrict__ out, int n4)
{
    for (int i = blockIdx.x*256 + threadIdx.x; i < n4; i += gridDim.x*256){
        const float4 v = reinterpret_cast<const float4*>(in)[i];
        ushort4 o;
        o.x = f2bf(v.x); o.y = f2bf(v.y); o.z = f2bf(v.z); o.w = f2bf(v.w);
        reinterpret_cast<ushort4*>(out)[i] = o;
    }
}

// ---------------------------------------------------------------------------
// Prep (IN PLACE inside u): per (b,h,chunk), per d: prefix over t of
// g = logsigmoid(lg). q slot <- silu(q)*exp(b); lg slot <- (1-sig(lg))*exp(-b).
// ---------------------------------------------------------------------------
__global__ __launch_bounds__(128) void gla_prep(
    float* __restrict__ u, float* __restrict__ BC)
{
    const int bid = blockIdx.x;               // (b*H + h)*NC + c
    const int c = bid % NC_;
    const int h = (bid / NC_) % H_;
    const int b = bid / (NC_*H_);
    const int d = threadIdx.x;
    const size_t urow0 = ((size_t)b*N_ + (size_t)c*CHUNK)*(3*E_) + (size_t)h*D_ + d;
    float bacc = 0.f;
    for (int t=0;t<CHUNK;t++){
        const size_t r = urow0 + (size_t)t*(3*E_);
        const float q  = u[r + E_];
        const float lg = u[r + 2*E_];
        const float sq = q * sigmoidf_(q);
        const float g  = (lg >= 0.f) ? -log1pf(__expf(-lg))
                                     : (lg - log1pf(__expf(lg)));
        const float kk = sigmoidf_(-lg);
        bacc += g;
        u[r + E_]   = sq * __expf(bacc);
        u[r + 2*E_] = kk * __expf(-bacc);
    }
    BC[(size_t)bid*D_ + d] = bacc;
}

// ---------------------------------------------------------------------------
// Chunk summary: Mc[d,e] = exp(BC[d]) * sum_s KIN[s,d] * V[s,e]
// ---------------------------------------------------------------------------
__global__ __launch_bounds__(256) void gla_chunk_sum(
    const float* __restrict__ u, const float* __restrict__ BC,
    float* __restrict__ Mc)
{
    __shared__ float kin_l[CHUNK*132];
    __shared__ float v_l[CHUNK*132];
    const int bid = blockIdx.x;
    const int c = bid % NC_;
    const int h = (bid / NC_) % H_;
    const int b = bid / (NC_*H_);
    const int tid = threadIdx.x;
    const int tx = tid & 15, ty = tid >> 4;
    const size_t urow0 = ((size_t)b*N_ + (size_t)c*CHUNK)*(3*E_) + (size_t)h*D_;
#pragma unroll
    for (int f = tid; f < CHUNK*32; f += 256){
        const int s = f >> 5, dq = (f & 31)*4;
        const float4 kv = *reinterpret_cast<const float4*>(&u[urow0 + 2*E_ + (size_t)s*(3*E_) + dq]);
        const float4 vv = *reinterpret_cast<const float4*>(&u[urow0 +        (size_t)s*(3*E_) + dq]);
        kin_l[s*132+dq+0]=kv.x; kin_l[s*132+dq+1]=kv.y; kin_l[s*132+dq+2]=kv.z; kin_l[s*132+dq+3]=kv.w;
        v_l  [s*132+dq+0]=vv.x; v_l  [s*132+dq+1]=vv.y; v_l  [s*132+dq+2]=vv.z; v_l  [s*132+dq+3]=vv.w;
    }
    __syncthreads();
    float acc[8][8];
#pragma unroll
    for (int i=0;i<8;i++)
#pragma unroll
        for (int j=0;j<8;j++) acc[i][j]=0.f;
    for (int s=0;s<CHUNK;s++){
        const float4 a0 = *reinterpret_cast<const float4*>(&kin_l[s*132 + 4*ty]);
        const float4 a1 = *reinterpret_cast<const float4*>(&kin_l[s*132 + 64 + 4*ty]);
        const float4 b0 = *reinterpret_cast<const float4*>(&v_l[s*132 + 4*tx]);
        const float4 b1 = *reinterpret_cast<const float4*>(&v_l[s*132 + 64 + 4*tx]);
        const float a[8]  = {a0.x,a0.y,a0.z,a0.w,a1.x,a1.y,a1.z,a1.w};
        const float bb[8] = {b0.x,b0.y,b0.z,b0.w,b1.x,b1.y,b1.z,b1.w};
#pragma unroll
        for (int i=0;i<8;i++)
#pragma unroll
            for (int j=0;j<8;j++)
                acc[i][j] = fmaf(a[i], bb[j], acc[i][j]);
    }
#pragma unroll
    for (int i=0;i<8;i++){
        const int dI = (i<4) ? (4*ty+i) : (64 + 4*ty + (i-4));
        const float dec = __expf(BC[(size_t)bid*D_ + dI]);
        float4 o0, o1;
        o0.x=acc[i][0]*dec; o0.y=acc[i][1]*dec; o0.z=acc[i][2]*dec; o0.w=acc[i][3]*dec;
        o1.x=acc[i][4]*dec; o1.y=acc[i][5]*dec; o1.z=acc[i][6]*dec; o1.w=acc[i][7]*dec;
        float* mp = &Mc[(size_t)bid*D_*D_ + (size_t)dI*D_];
        *reinterpret_cast<float4*>(&mp[4*tx])      = o0;
        *reinterpret_cast<float4*>(&mp[64 + 4*tx]) = o1;
    }
}

// ---------------------------------------------------------------------------
// Inter-chunk scan, in place. After: McS[c] = state at START of chunk c.
// ---------------------------------------------------------------------------
__global__ __launch_bounds__(256) void gla_scan_chunks(
    float* __restrict__ McS, const float* __restrict__ BC)
{
    const size_t F = (size_t)blockIdx.x*256 + threadIdx.x;
    const int bh = (int)(F >> 14);
    const int rem = (int)(F & 16383);
    const int d = rem >> 7;
    float Scur = 0.f;
    for (int c=0;c<NC_;c++){
        const size_t idx = (((size_t)bh*NC_ + c) << 14) + rem;
        const float m = McS[idx];
        const float dec = __expf(BC[((size_t)bh*NC_ + c)*D_ + d]);
        McS[idx] = Scur;
        Scur = dec*Scur + m;
    }
}

// ---------------------------------------------------------------------------
// Output: per (b,h,chunk): A = causal(QS@KIN^T); O = A@V + QS@S_start.
// ---------------------------------------------------------------------------
__global__ __launch_bounds__(256) void gla_output(
    const float* __restrict__ u, const float* __restrict__ S,
    float* __restrict__ Opre)
{
    __shared__ float qs_l[CHUNK*132];
    __shared__ float kv_l[CHUNK*132];
    __shared__ float a_l[CHUNK*68];
    const int bid = blockIdx.x;
    const int c = bid % NC_;
    const int h = (bid / NC_) % H_;
    const int b = bid / (NC_*H_);
    const int tid = threadIdx.x;
    const int tx = tid & 15, ty = tid >> 4;
    const size_t urow0 = ((size_t)b*N_ + (size_t)c*CHUNK)*(3*E_) + (size_t)h*D_;
#pragma unroll
    for (int f = tid; f < CHUNK*32; f += 256){
        const int s = f >> 5, dq = (f & 31)*4;
        const float4 qv = *reinterpret_cast<const float4*>(&u[urow0 +   E_ + (size_t)s*(3*E_) + dq]);
        const float4 kv = *reinterpret_cast<const float4*>(&u[urow0 + 2*E_ + (size_t)s*(3*E_) + dq]);
        qs_l[s*132+dq+0]=qv.x; qs_l[s*132+dq+1]=qv.y; qs_l[s*132+dq+2]=qv.z; qs_l[s*132+dq+3]=qv.w;
        kv_l[s*132+dq+0]=kv.x; kv_l[s*132+dq+1]=kv.y; kv_l[s*132+dq+2]=kv.z; kv_l[s*132+dq+3]=kv.w;
    }
    __syncthreads();
    float pa[4][4];
#pragma unroll
    for (int i=0;i<4;i++)
#pragma unroll
        for (int j=0;j<4;j++) pa[i][j]=0.f;
    for (int d=0; d<D_; d++){
        float a[4], bb[4];
#pragma unroll
        for (int i=0;i<4;i++) a[i]  = qs_l[(4*ty+i)*132 + d];
#pragma unroll
        for (int j=0;j<4;j++) bb[j] = kv_l[(4*tx+j)*132 + d];
#pragma unroll
        for (int i=0;i<4;i++)
#pragma unroll
            for (int j=0;j<4;j++)
                pa[i][j] = fmaf(a[i], bb[j], pa[i][j]);
    }
    __syncthreads();
#pragma unroll
    for (int i=0;i<4;i++)
#pragma unroll
        for (int j=0;j<4;j++){
            const int t = 4*ty+i, s = 4*tx+j;
            a_l[t*68 + s] = (t >= s) ? pa[i][j] : 0.f;
        }
#pragma unroll
    for (int f = tid; f < CHUNK*32; f += 256){
        const int s = f >> 5, dq = (f & 31)*4;
        const float4 vv = *reinterpret_cast<const float4*>(&u[urow0 + (size_t)s*(3*E_) + dq]);
        kv_l[s*132+dq+0]=vv.x; kv_l[s*132+dq+1]=vv.y; kv_l[s*132+dq+2]=vv.z; kv_l[s*132+dq+3]=vv.w;
    }
    __syncthreads();
    float o[4][8];
#pragma unroll
    for (int i=0;i<4;i++)
#pragma unroll
        for (int j=0;j<8;j++) o[i][j]=0.f;
    for (int s=0;s<CHUNK;s++){
        float a[4];
#pragma unroll
        for (int i=0;i<4;i++) a[i] = a_l[(4*ty+i)*68 + s];
        const float4 v0 = *reinterpret_cast<const float4*>(&kv_l[s*132 + 4*tx]);
        const float4 v1 = *reinterpret_cast<const float4*>(&kv_l[s*132 + 64 + 4*tx]);
        const float vv[8] = {v0.x,v0.y,v0.z,v0.w,v1.x,v1.y,v1.z,v1.w};
#pragma unroll
        for (int i=0;i<4;i++)
#pragma unroll
            for (int j=0;j<8;j++)
                o[i][j] = fmaf(a[i], vv[j], o[i][j]);
    }
    const float* Sb = &S[(size_t)bid*D_*D_];
    for (int d0=0; d0<D_; d0+=16){
        __syncthreads();
#pragma unroll
        for (int f=tid; f<16*32; f+=256){
            const int dr = f >> 5, dq = (f & 31)*4;
            const float4 sv = *reinterpret_cast<const float4*>(&Sb[(size_t)(d0+dr)*D_ + dq]);
            a_l[dr*132+dq+0]=sv.x; a_l[dr*132+dq+1]=sv.y; a_l[dr*132+dq+2]=sv.z; a_l[dr*132+dq+3]=sv.w;
        }
        __syncthreads();
#pragma unroll
        for (int dd=0; dd<16; dd++){
            float a[4];
#pragma unroll
            for (int i=0;i<4;i++) a[i] = qs_l[(4*ty+i)*132 + d0+dd];
            const float4 s0 = *reinterpret_cast<const float4*>(&a_l[dd*132 + 4*tx]);
            const float4 s1 = *reinterpret_cast<const float4*>(&a_l[dd*132 + 64 + 4*tx]);
            const float ss[8] = {s0.x,s0.y,s0.z,s0.w,s1.x,s1.y,s1.z,s1.w};
#pragma unroll
            for (int i=0;i<4;i++)
#pragma unroll
                for (int j=0;j<8;j++)
                    o[i][j] = fmaf(a[i], ss[j], o[i][j]);
        }
    }
#pragma unroll
    for (int i=0;i<4;i++){
        const int t = 4*ty + i;
        const size_t orow = ((size_t)b*N_ + (size_t)c*CHUNK + t)*E_ + (size_t)h*D_;
        float4 o0, o1;
        o0.x=o[i][0]; o0.y=o[i][1]; o0.z=o[i][2]; o0.w=o[i][3];
        o1.x=o[i][4]; o1.y=o[i][5]; o1.z=o[i][6]; o1.w=o[i][7];
        *reinterpret_cast<float4*>(&Opre[orow + 4*tx])      = o0;
        *reinterpret_cast<float4*>(&Opre[orow + 64 + 4*tx]) = o1;
    }
}

// ---------------------------------------------------------------------------
// Gate + LayerNorm; writes bf16 (feeds the final MFMA GEMM).
// ---------------------------------------------------------------------------
__global__ __launch_bounds__(256) void gate_ln_bf16(
    const float* __restrict__ O, const float* __restrict__ G2,
    const float* __restrict__ lnw, unsigned short* __restrict__ Ob)
{
    const int row = blockIdx.x;
    const int tid = threadIdx.x;
    const size_t off = (size_t)row*E_ + tid*4;
    float4 o = *reinterpret_cast<const float4*>(&O[off]);
    const float4 g = *reinterpret_cast<const float4*>(&G2[off]);
    o.x *= sigmoidf_(g.x); o.y *= sigmoidf_(g.y);
    o.z *= sigmoidf_(g.z); o.w *= sigmoidf_(g.w);
    float s1 = o.x+o.y+o.z+o.w;
    float s2 = o.x*o.x + o.y*o.y + o.z*o.z + o.w*o.w;
#pragma unroll
    for (int sh=32; sh>0; sh>>=1){
        s1 += __shfl_down(s1, sh);
        s2 += __shfl_down(s2, sh);
    }
    __shared__ float r1[4], r2[4];
    const int wid = tid >> 6;
    if ((tid & 63)==0){ r1[wid]=s1; r2[wid]=s2; }
    __syncthreads();
    s1 = r1[0]+r1[1]+r1[2]+r1[3];
    s2 = r2[0]+r2[1]+r2[2]+r2[3];
    const float mean = s1 * (1.f/E_);
    const float var  = s2 * (1.f/E_) - mean*mean;
    const float rs   = rsqrtf(var + 1e-5f);
    const float4 w = *reinterpret_cast<const float4*>(&lnw[tid*4]);
    ushort4 r;
    r.x = f2bf((o.x-mean)*rs*w.x); r.y = f2bf((o.y-mean)*rs*w.y);
    r.z = f2bf((o.z-mean)*rs*w.z); r.w = f2bf((o.w-mean)*rs*w.w);
    *reinterpret_cast<ushort4*>(&Ob[off]) = r;
}

// ---------------------------------------------------------------------------
extern "C" void kernel_launch(void* const* d_in, const int* in_sizes, int n_in,
                              void* d_out, int out_size, void* d_ws, size_t ws_size,
                              hipStream_t stream)
{
    const float* x     = (const float*)d_in[0];
    const float* W_in  = (const float*)d_in[1];
    const float* W_out = (const float*)d_in[2];
    const float* W_g1  = (const float*)d_in[3];
    const float* W_g2  = (const float*)d_in[4];
    const float* lnw   = (const float*)d_in[5];
    float* out = (float*)d_out;
    char* ws = (char*)d_ws;

    // workspace layout (bytes); total 246,415,360 (< 256 MiB)
    float*          u      = (float*)(ws);                  // [B,N,3E]    100,663,296
    float*          BC     = (float*)(ws + 100663296);      //                 524,288
    float*          Mc     = (float*)(ws + 101187584);      //              67,108,864
    float*          Opre   = (float*)(ws + 168296448);      //              33,554,432
    unsigned short* xb     = (unsigned short*)(ws + 201850880); //          16,777,216
    unsigned short* W_inb  = (unsigned short*)(ws + 218628096); //           6,291,456
    unsigned short* W_outb = (unsigned short*)(ws + 224919552); //           2,097,152
    unsigned short* W_g1b  = (unsigned short*)(ws + 227016704); //             262,144
    unsigned short* W_g2b  = (unsigned short*)(ws + 227278848); //             262,144
    unsigned short* G1b    = (unsigned short*)(ws + 227540992); //           2,097,152
    unsigned short* ObF    = (unsigned short*)(ws + 229638144); //          16,777,216
    float*          G2f    = u;   // reuse u after gla_output

    const int M = B_*N_;     // 8192
    dim3 blk(256);

    // casts to bf16
    cast_bf16<<<2048, blk, 0, stream>>>(x,     xb,     (B_*N_*E_)/4);
    cast_bf16<<<2048, blk, 0, stream>>>(W_in,  W_inb,  (3*E_*E_)/4);
    cast_bf16<<<1024, blk, 0, stream>>>(W_out, W_outb, (E_*E_)/4);
    cast_bf16<<<128,  blk, 0, stream>>>(W_g1,  W_g1b,  (D_*E_)/4);
    cast_bf16<<<128,  blk, 0, stream>>>(W_g2,  W_g2b,  (E_*D_)/4);

    // 1) u = x @ W_in^T  (f32 out)
    gemm_bf16<false><<<dim3(3*E_/128, M/128), blk, 0, stream>>>(xb, W_inb, u, M, 3*E_, E_);
    // 2) decay-scaled q,k + chunk prefix sums (in place in u)
    gla_prep<<<dim3(B_*H_*NC_), dim3(128), 0, stream>>>(u, BC);
    // 3) per-chunk summaries
    gla_chunk_sum<<<dim3(B_*H_*NC_), blk, 0, stream>>>(u, BC, Mc);
    // 4) inter-chunk scan
    gla_scan_chunks<<<dim3((B_*H_*D_*D_)/256), blk, 0, stream>>>(Mc, BC);
    // 5) per-chunk outputs
    gla_output<<<dim3(B_*H_*NC_), blk, 0, stream>>>(u, Mc, Opre);
    // 6) G1 = x @ W_g1^T  (bf16 out)
    gemm_bf16<true><<<dim3(1, M/128), blk, 0, stream>>>(xb, W_g1b, G1b, M, D_, E_);
    // 7) G2 = G1 @ W_g2^T (f32 out, into u which is now dead)
    gemm_bf16<false><<<dim3(E_/128, M/128), blk, 0, stream>>>(G1b, W_g2b, G2f, M, E_, D_);
    // 8) gate + layernorm -> bf16
    gate_ln_bf16<<<dim3(M), blk, 0, stream>>>(Opre, G2f, lnw, ObF);
    // 9) out = LN(o) @ W_out^T
    gemm_bf16<false><<<dim3(E_/128, M/128), blk, 0, stream>>>(ObF, W_outb, out, M, E_, E_);
}

// Round 4
// 339.080 us; speedup vs baseline: 3.4983x; 1.2964x over previous
//
#include <hip/hip_runtime.h>
#include <cmath>

#define B_ 2
#define N_ 4096
#define E_ 1024
#define D_ 128
#define H_ 8
#define CHUNK 64
#define NC_ (N_/CHUNK)   // 64

__device__ __forceinline__ float sigmoidf_(float x){ return 1.f/(1.f + __expf(-x)); }

__device__ __forceinline__ unsigned short f2bf(float f){
    unsigned u = __float_as_uint(f);
    u += 0x7FFFu + ((u >> 16) & 1u);      // round-to-nearest-even
    return (unsigned short)(u >> 16);
}

typedef __attribute__((ext_vector_type(8))) __bf16 bf16x8;
typedef __attribute__((ext_vector_type(4))) float  f32x4;
typedef __attribute__((address_space(3))) unsigned int as3_u32;
typedef __attribute__((address_space(1))) unsigned int as1_u32;

__device__ __forceinline__ void gload_lds16(const void* g, void* l){
    __builtin_amdgcn_global_load_lds((as1_u32*)g, (as3_u32*)l, 16, 0, 0);
}

// fragment load from LDS tile with 256B rows (128 bf16/row), XOR-swizzled
__device__ __forceinline__ bf16x8 ldsfrag256(const unsigned short* Lp, int row, int kg){
    return *reinterpret_cast<const bf16x8*>(&Lp[row*128 + ((kg ^ (row&7))<<3)]);
}
// fragment load from LDS tile with 128B rows (64 bf16/row)
__device__ __forceinline__ bf16x8 ldsfrag128(const unsigned short* Lp, int row, int kg){
    return *reinterpret_cast<const bf16x8*>(&Lp[row*64 + ((kg ^ (row&7))<<3)]);
}

// ---------------------------------------------------------------------------
// bf16 MFMA GEMM: C[M,N] = A[M,K] @ Bw[N,K]^T  (unchanged from round 3)
// ---------------------------------------------------------------------------
template<bool OUT_BF16>
__global__ __launch_bounds__(256) void gemm_bf16(
    const unsigned short* __restrict__ A,
    const unsigned short* __restrict__ Bw,
    void* __restrict__ Cout, int M, int N, int K)
{
    __shared__ unsigned short As[128*64];
    __shared__ unsigned short Bs[128*64];
    const int tid  = threadIdx.x;
    const int wave = tid >> 6;
    const int lane = tid & 63;
    const int m0 = blockIdx.y * 128, n0 = blockIdx.x * 128;
    const int wr = (wave >> 1) * 64;
    const int wc = (wave & 1) * 64;
    const int l15 = lane & 15, l4 = lane >> 4;
    const int p = l15 & 7;

    f32x4 acc[4][4];
#pragma unroll
    for (int i=0;i<4;i++)
#pragma unroll
        for (int j=0;j<4;j++)
#pragma unroll
            for (int q=0;q<4;q++) acc[i][j][q]=0.f;

    const int srow = wave*32 + (lane>>3);
    const int sgrp = lane & 7;

    for (int k0=0; k0<K; k0+=64){
        if (k0) __syncthreads();
#pragma unroll
        for (int i=0;i<4;i++){
            const int r  = srow + 8*i;
            const int cg = sgrp ^ (r & 7);
            gload_lds16(A  + (size_t)(m0 + r)*K + k0 + cg*8, &As[(wave*32 + 8*i)*64]);
            gload_lds16(Bw + (size_t)(n0 + r)*K + k0 + cg*8, &Bs[(wave*32 + 8*i)*64]);
        }
        __syncthreads();
#pragma unroll
        for (int ks=0; ks<2; ks++){
            bf16x8 av[4], bv[4];
            const int tA = (((ks<<2) | l4) ^ p) << 3;
#pragma unroll
            for (int f=0; f<4; f++){
                const int rowA = wr + f*16 + l15;
                const int rowB = wc + f*16 + l15;
                av[f] = *reinterpret_cast<const bf16x8*>(&As[(rowA<<6) + tA]);
                bv[f] = *reinterpret_cast<const bf16x8*>(&Bs[(rowB<<6) + tA]);
            }
#pragma unroll
            for (int fm=0; fm<4; fm++)
#pragma unroll
                for (int fn=0; fn<4; fn++)
                    acc[fm][fn] = __builtin_amdgcn_mfma_f32_16x16x32_bf16(
                        av[fm], bv[fn], acc[fm][fn], 0, 0, 0);
        }
    }
    const int crow0 = m0 + wr + l4*4;
    const int ccol0 = n0 + wc + l15;
    if (!OUT_BF16){
        float* C = (float*)Cout;
#pragma unroll
        for (int fm=0; fm<4; fm++)
#pragma unroll
            for (int fn=0; fn<4; fn++)
#pragma unroll
                for (int j=0;j<4;j++)
                    C[(size_t)(crow0 + fm*16 + j)*N + ccol0 + fn*16] = acc[fm][fn][j];
    } else {
        unsigned short* C = (unsigned short*)Cout;
#pragma unroll
        for (int fm=0; fm<4; fm++)
#pragma unroll
            for (int fn=0; fn<4; fn++)
#pragma unroll
                for (int j=0;j<4;j++)
                    C[(size_t)(crow0 + fm*16 + j)*N + ccol0 + fn*16] = f2bf(acc[fm][fn][j]);
    }
}

// ---------------------------------------------------------------------------
__global__ __launch_bounds__(256) void cast_bf16(
    const float* __restrict__ in, unsigned short* __restrict__ out, int n4)
{
    for (int i = blockIdx.x*256 + threadIdx.x; i < n4; i += gridDim.x*256){
        const float4 v = reinterpret_cast<const float4*>(in)[i];
        ushort4 o;
        o.x = f2bf(v.x); o.y = f2bf(v.y); o.z = f2bf(v.z); o.w = f2bf(v.w);
        reinterpret_cast<ushort4*>(out)[i] = o;
    }
}

// ---------------------------------------------------------------------------
// Prep: per (b,h,chunk), per d: prefix b_t = sum logsigmoid(lg).
// Emits bf16: QS[t,d] = silu(q)*exp(b_t);  KIN[s,d] = (1-sig)*exp(-b_s);
//             KIN2t[d,s] = (1-sig)*exp(BC_d - b_s)  (<=1, transposed);
//             Vt[e,s] = v transposed.  Plus BC[d] (f32).
// ---------------------------------------------------------------------------
__global__ __launch_bounds__(128) void gla_prep(
    const float* __restrict__ u, float* __restrict__ BC,
    unsigned short* __restrict__ QSb, unsigned short* __restrict__ KINb,
    unsigned short* __restrict__ KINtb, unsigned short* __restrict__ Vtb)
{
    __shared__ float kin_l[128*65];
    __shared__ float v_l[128*65];
    __shared__ float bc_l[128];
    const int bid = blockIdx.x;               // (b*H+h)*NC + c
    const int c = bid % NC_;
    const int h = (bid / NC_) % H_;
    const int b = bid / (NC_*H_);
    const int d = threadIdx.x;
    const size_t urow0 = ((size_t)b*N_ + (size_t)c*CHUNK)*(3*E_) + (size_t)h*D_ + d;
    const size_t obase = (size_t)bid*CHUNK*D_;
    float bacc = 0.f;
    for (int t=0;t<CHUNK;t++){
        const size_t r = urow0 + (size_t)t*(3*E_);
        const float vv = u[r];
        const float q  = u[r + E_];
        const float lg = u[r + 2*E_];
        const float sq = q * sigmoidf_(q);
        const float g  = (lg >= 0.f) ? -log1pf(__expf(-lg))
                                     : (lg - log1pf(__expf(lg)));
        const float kk = sigmoidf_(-lg);
        bacc += g;
        QSb[obase + (size_t)t*D_ + d] = f2bf(sq * __expf(bacc));
        const float kin = kk * __expf(-bacc);
        KINb[obase + (size_t)t*D_ + d] = f2bf(kin);
        kin_l[d*65 + t] = kin;
        v_l  [d*65 + t] = vv;
    }
    bc_l[d] = __expf(bacc);   // exp(BC_d)
    BC[(size_t)bid*D_ + d] = bacc;
    __syncthreads();
    // transpose-write KIN2t[d][s], Vt[d][s] — coalesced 256B per iteration
    const size_t tbase = (size_t)bid*D_*CHUNK;
    for (int base=0; base<D_*CHUNK; base+=128){
        const int idx = base + threadIdx.x;
        const int dd = idx >> 6, ss = idx & 63;
        const float eb = bc_l[dd];
        KINtb[tbase + idx] = f2bf(kin_l[dd*65+ss] * eb);
        Vtb  [tbase + idx] = f2bf(v_l[dd*65+ss]);
    }
}

// ---------------------------------------------------------------------------
// Batched chunk summary (MFMA): McT[bid][e][d] = sum_s Vt[e,s] * KIN2t[d,s]
// 128x128 out, K=64. One block per (b,h,chunk), 4 waves.
// ---------------------------------------------------------------------------
__global__ __launch_bounds__(256) void gla_chunk_mm(
    const unsigned short* __restrict__ Vtb,
    const unsigned short* __restrict__ KINtb,
    float* __restrict__ McT)
{
    __shared__ unsigned short As[128*64];
    __shared__ unsigned short Bs[128*64];
    const int bid = blockIdx.x;
    const int tid = threadIdx.x;
    const int w = tid >> 6, lane = tid & 63;
    const int l15 = lane & 15, l4 = lane >> 4;
    const int wr = (w >> 1) * 64, wc = (w & 1) * 64;
    const unsigned short* A  = Vtb   + (size_t)bid*128*64;
    const unsigned short* Bp = KINtb + (size_t)bid*128*64;

    f32x4 acc[4][4];
#pragma unroll
    for (int i=0;i<4;i++)
#pragma unroll
        for (int j=0;j<4;j++)
#pragma unroll
            for (int q=0;q<4;q++) acc[i][j][q]=0.f;

#pragma unroll
    for (int i=0;i<4;i++){
        const int r  = w*32 + i*8 + (lane>>3);
        const int gs = (lane&7) ^ (r&7);
        gload_lds16(A  + (size_t)r*64 + gs*8, &As[(w*32+i*8)*64]);
        gload_lds16(Bp + (size_t)r*64 + gs*8, &Bs[(w*32+i*8)*64]);
    }
    __syncthreads();
#pragma unroll
    for (int ks=0; ks<2; ks++){
        bf16x8 av[4], bv[4];
#pragma unroll
        for (int f=0; f<4; f++){
            av[f] = ldsfrag128(As, wr + f*16 + l15, ks*4 + l4);
            bv[f] = ldsfrag128(Bs, wc + f*16 + l15, ks*4 + l4);
        }
#pragma unroll
        for (int fm=0; fm<4; fm++)
#pragma unroll
            for (int fn=0; fn<4; fn++)
                acc[fm][fn] = __builtin_amdgcn_mfma_f32_16x16x32_bf16(
                    av[fm], bv[fn], acc[fm][fn], 0, 0, 0);
    }
    float* C = McT + (size_t)bid*128*128;
#pragma unroll
    for (int fm=0; fm<4; fm++)
#pragma unroll
        for (int fn=0; fn<4; fn++)
#pragma unroll
            for (int j=0;j<4;j++)
                C[(size_t)(wr + fm*16 + l4*4 + j)*128 + wc + fn*16 + l15] = acc[fm][fn][j];
}

// ---------------------------------------------------------------------------
// Inter-chunk scan over McT[e][d]; writes bf16 chunk-START states only.
// ---------------------------------------------------------------------------
__global__ __launch_bounds__(256) void gla_scan_chunks(
    const float* __restrict__ McT, const float* __restrict__ BC,
    unsigned short* __restrict__ Sb16)
{
    const size_t F = (size_t)blockIdx.x*256 + threadIdx.x;   // < B*H*D*D
    const int bh = (int)(F >> 14);
    const int rem = (int)(F & 16383);
    const int d = rem & 127;                                 // col of McT
    float S = 0.f;
    for (int c=0;c<NC_;c++){
        const size_t idx = (((size_t)bh*NC_ + c) << 14) + rem;
        const float m = McT[idx];
        const float dec = __expf(BC[((size_t)bh*NC_ + c)*D_ + d]);
        Sb16[idx] = f2bf(S);
        S = dec*S + m;
    }
}

// ---------------------------------------------------------------------------
// Output (MFMA): per (b,h,chunk):
//   A[t,s] = causal(QS @ KIN^T);  O = A @ Vt^T + QS @ S^T  -> Opre [B,N,E] f32
// 4 waves: phase A each wave owns 16 s-cols; phase B each wave owns 32 e-cols.
// ---------------------------------------------------------------------------
__global__ __launch_bounds__(256) void gla_output(
    const unsigned short* __restrict__ QSb,
    const unsigned short* __restrict__ KINb,
    const unsigned short* __restrict__ Vtb,
    const unsigned short* __restrict__ Sb,
    float* __restrict__ Opre)
{
    __shared__ unsigned short QS_l[64*128];
    __shared__ unsigned short KA_l[64*128];   // KIN; first 8KB reused for A
    __shared__ unsigned short Vt_l[128*64];
    __shared__ unsigned short S_l [128*128];
    const int bid = blockIdx.x;
    const int c = bid % NC_;
    const int h = (bid / NC_) % H_;
    const int b = bid / (NC_*H_);
    const int tid = threadIdx.x;
    const int w = tid >> 6, lane = tid & 63;
    const int l15 = lane & 15, l4 = lane >> 4;

    {   // ---- stage (pre-swizzled sources, linear LDS dest) ----
        const unsigned short* q = QSb + (size_t)bid*64*128;
        const unsigned short* k = KINb + (size_t)bid*64*128;
        const unsigned short* v = Vtb + (size_t)bid*128*64;
        const unsigned short* s = Sb  + (size_t)bid*128*128;
#pragma unroll
        for (int i=0;i<4;i++){
            const int r  = w*16 + i*4 + (lane>>4);
            const int gs = (lane&15) ^ (r&7);
            gload_lds16(q + (size_t)r*128 + gs*8, &QS_l[(w*16+i*4)*128]);
            gload_lds16(k + (size_t)r*128 + gs*8, &KA_l[(w*16+i*4)*128]);
        }
#pragma unroll
        for (int i=0;i<4;i++){
            const int r  = w*32 + i*8 + (lane>>3);
            const int gs = (lane&7) ^ (r&7);
            gload_lds16(v + (size_t)r*64 + gs*8, &Vt_l[(w*32+i*8)*64]);
        }
#pragma unroll
        for (int i=0;i<8;i++){
            const int r  = w*32 + i*4 + (lane>>4);
            const int gs = (lane&15) ^ (r&7);
            gload_lds16(s + (size_t)r*128 + gs*8, &S_l[(w*32+i*4)*128]);
        }
    }
    __syncthreads();

    // ---- phase A: A[t, w*16 + l15] ----
    f32x4 accA[4];
#pragma unroll
    for (int i=0;i<4;i++)
#pragma unroll
        for (int q=0;q<4;q++) accA[i][q]=0.f;
    const int srow = w*16 + l15;
#pragma unroll
    for (int ks=0; ks<4; ks++){
        const bf16x8 bv = ldsfrag256(KA_l, srow, ks*4 + l4);
#pragma unroll
        for (int ft=0; ft<4; ft++){
            const bf16x8 av = ldsfrag256(QS_l, ft*16 + l15, ks*4 + l4);
            accA[ft] = __builtin_amdgcn_mfma_f32_16x16x32_bf16(av, bv, accA[ft], 0,0,0);
        }
    }
    __syncthreads();            // all KIN reads done before A overwrite
    // mask & write bf16 A into KA_l[0:4096] as [t][s] (128B rows, swizzled)
#pragma unroll
    for (int ft=0; ft<4; ft++)
#pragma unroll
        for (int j=0;j<4;j++){
            const int t = ft*16 + l4*4 + j;
            const int s = w*16 + l15;
            const float vA = (t >= s) ? accA[ft][j] : 0.f;
            KA_l[t*64 + (((s>>3) ^ (t&7))<<3) + (s&7)] = f2bf(vA);
        }
    __syncthreads();

    // ---- phase B: O[t, e-slab w] = A @ Vt^T + QS @ S^T ----
    f32x4 acc[4][2];
#pragma unroll
    for (int i=0;i<4;i++)
#pragma unroll
        for (int j=0;j<2;j++)
#pragma unroll
            for (int q=0;q<4;q++) acc[i][j][q]=0.f;
#pragma unroll
    for (int ks=0; ks<2; ks++){                 // O1: K = s = 64
        bf16x8 bv[2];
        bv[0] = ldsfrag128(Vt_l, w*32 +      l15, ks*4 + l4);
        bv[1] = ldsfrag128(Vt_l, w*32 + 16 + l15, ks*4 + l4);
#pragma unroll
        for (int ft=0; ft<4; ft++){
            const bf16x8 av = ldsfrag128(KA_l, ft*16 + l15, ks*4 + l4);
            acc[ft][0] = __builtin_amdgcn_mfma_f32_16x16x32_bf16(av, bv[0], acc[ft][0], 0,0,0);
            acc[ft][1] = __builtin_amdgcn_mfma_f32_16x16x32_bf16(av, bv[1], acc[ft][1], 0,0,0);
        }
    }
#pragma unroll
    for (int ks=0; ks<4; ks++){                 // O2: K = d = 128
        bf16x8 bv[2];
        bv[0] = ldsfrag256(S_l, w*32 +      l15, ks*4 + l4);
        bv[1] = ldsfrag256(S_l, w*32 + 16 + l15, ks*4 + l4);
#pragma unroll
        for (int ft=0; ft<4; ft++){
            const bf16x8 av = ldsfrag256(QS_l, ft*16 + l15, ks*4 + l4);
            acc[ft][0] = __builtin_amdgcn_mfma_f32_16x16x32_bf16(av, bv[0], acc[ft][0], 0,0,0);
            acc[ft][1] = __builtin_amdgcn_mfma_f32_16x16x32_bf16(av, bv[1], acc[ft][1], 0,0,0);
        }
    }
    const size_t rowbase = (size_t)b*N_ + (size_t)c*CHUNK;
#pragma unroll
    for (int ft=0; ft<4; ft++)
#pragma unroll
        for (int fe=0; fe<2; fe++)
#pragma unroll
            for (int j=0;j<4;j++){
                const int t = ft*16 + l4*4 + j;
                const int e = w*32 + fe*16 + l15;
                Opre[(rowbase + t)*E_ + h*D_ + e] = acc[ft][fe][j];
            }
}

// ---------------------------------------------------------------------------
// Gate + LayerNorm -> bf16
// ---------------------------------------------------------------------------
__global__ __launch_bounds__(256) void gate_ln_bf16(
    const float* __restrict__ O, const float* __restrict__ G2,
    const float* __restrict__ lnw, unsigned short* __restrict__ Ob)
{
    const int row = blockIdx.x;
    const int tid = threadIdx.x;
    const size_t off = (size_t)row*E_ + tid*4;
    float4 o = *reinterpret_cast<const float4*>(&O[off]);
    const float4 g = *reinterpret_cast<const float4*>(&G2[off]);
    o.x *= sigmoidf_(g.x); o.y *= sigmoidf_(g.y);
    o.z *= sigmoidf_(g.z); o.w *= sigmoidf_(g.w);
    float s1 = o.x+o.y+o.z+o.w;
    float s2 = o.x*o.x + o.y*o.y + o.z*o.z + o.w*o.w;
#pragma unroll
    for (int sh=32; sh>0; sh>>=1){
        s1 += __shfl_down(s1, sh);
        s2 += __shfl_down(s2, sh);
    }
    __shared__ float r1[4], r2[4];
    const int wid = tid >> 6;
    if ((tid & 63)==0){ r1[wid]=s1; r2[wid]=s2; }
    __syncthreads();
    s1 = r1[0]+r1[1]+r1[2]+r1[3];
    s2 = r2[0]+r2[1]+r2[2]+r2[3];
    const float mean = s1 * (1.f/E_);
    const float var  = s2 * (1.f/E_) - mean*mean;
    const float rs   = rsqrtf(var + 1e-5f);
    const float4 w = *reinterpret_cast<const float4*>(&lnw[tid*4]);
    ushort4 r;
    r.x = f2bf((o.x-mean)*rs*w.x); r.y = f2bf((o.y-mean)*rs*w.y);
    r.z = f2bf((o.z-mean)*rs*w.z); r.w = f2bf((o.w-mean)*rs*w.w);
    *reinterpret_cast<ushort4*>(&Ob[off]) = r;
}

// ---------------------------------------------------------------------------
extern "C" void kernel_launch(void* const* d_in, const int* in_sizes, int n_in,
                              void* d_out, int out_size, void* d_ws, size_t ws_size,
                              hipStream_t stream)
{
    const float* x     = (const float*)d_in[0];
    const float* W_in  = (const float*)d_in[1];
    const float* W_out = (const float*)d_in[2];
    const float* W_g1  = (const float*)d_in[3];
    const float* W_g2  = (const float*)d_in[4];
    const float* lnw   = (const float*)d_in[5];
    float* out = (float*)d_out;
    char* ws = (char*)d_ws;

    // workspace layout (bytes); total 246,415,360 (< 256 MiB)
    float*          u      = (float*)(ws);                      // [B,N,3E] f32; reused:
    float*          McT    = (float*)(ws);                      //   [B,H,NC,D,D] f32  67,108,864
    unsigned short* Sb16   = (unsigned short*)(ws + 67108864);  //   [B,H,NC,D,D] bf16 33,554,432
    float*          BC     = (float*)(ws + 100663296);          //       524,288
    unsigned short* QSb    = (unsigned short*)(ws + 101187584); //    16,777,216
    unsigned short* KINb   = (unsigned short*)(ws + 117964800); //    16,777,216
    unsigned short* KINtb  = (unsigned short*)(ws + 134742016); //    16,777,216
    unsigned short* Vtb    = (unsigned short*)(ws + 151519232); //    16,777,216
    float*          Opre   = (float*)(ws + 168296448);          //    33,554,432
    unsigned short* xb     = (unsigned short*)(ws + 201850880); //    16,777,216
    unsigned short* W_inb  = (unsigned short*)(ws + 218628096); //     6,291,456
    unsigned short* W_outb = (unsigned short*)(ws + 224919552); //     2,097,152
    unsigned short* W_g1b  = (unsigned short*)(ws + 227016704); //       262,144
    unsigned short* W_g2b  = (unsigned short*)(ws + 227278848); //       262,144
    unsigned short* G1b    = (unsigned short*)(ws + 227540992); //     2,097,152
    unsigned short* ObF    = (unsigned short*)(ws + 229638144); //    16,777,216
    float*          G2f    = (float*)(ws + 101187584);          // reuse QSb+KINb (dead)

    const int M = B_*N_;     // 8192
    dim3 blk(256);

    // casts to bf16
    cast_bf16<<<2048, blk, 0, stream>>>(x,     xb,     (B_*N_*E_)/4);
    cast_bf16<<<2048, blk, 0, stream>>>(W_in,  W_inb,  (3*E_*E_)/4);
    cast_bf16<<<1024, blk, 0, stream>>>(W_out, W_outb, (E_*E_)/4);
    cast_bf16<<<128,  blk, 0, stream>>>(W_g1,  W_g1b,  (D_*E_)/4);
    cast_bf16<<<128,  blk, 0, stream>>>(W_g2,  W_g2b,  (E_*D_)/4);

    // 1) u = x @ W_in^T  (f32 out)
    gemm_bf16<false><<<dim3(3*E_/128, M/128), blk, 0, stream>>>(xb, W_inb, u, M, 3*E_, E_);
    // 2) prep: bf16 QS/KIN + transposed KIN2t/Vt + BC   (u dead after this)
    gla_prep<<<dim3(B_*H_*NC_), dim3(128), 0, stream>>>(u, BC, QSb, KINb, KINtb, Vtb);
    // 3) per-chunk summaries McT[e][d] (MFMA), into old u region
    gla_chunk_mm<<<dim3(B_*H_*NC_), blk, 0, stream>>>(Vtb, KINtb, McT);
    // 4) inter-chunk scan -> bf16 start states
    gla_scan_chunks<<<dim3((B_*H_*D_*D_)/256), blk, 0, stream>>>(McT, BC, Sb16);
    // 5) per-chunk outputs (MFMA)
    gla_output<<<dim3(B_*H_*NC_), blk, 0, stream>>>(QSb, KINb, Vtb, Sb16, Opre);
    // 6) G1 = x @ W_g1^T  (bf16 out)
    gemm_bf16<true><<<dim3(1, M/128), blk, 0, stream>>>(xb, W_g1b, G1b, M, D_, E_);
    // 7) G2 = G1 @ W_g2^T (f32 out, over dead QSb/KINb)
    gemm_bf16<false><<<dim3(E_/128, M/128), blk, 0, stream>>>(G1b, W_g2b, G2f, M, E_, D_);
    // 8) gate + layernorm -> bf16
    gate_ln_bf16<<<dim3(M), blk, 0, stream>>>(Opre, G2f, lnw, ObF);
    // 9) out = LN(o) @ W_out^T
    gemm_bf16<false><<<dim3(E_/128, M/128), blk, 0, stream>>>(ObF, W_outb, out, M, E_, E_);
}

// Round 5
// 284.078 us; speedup vs baseline: 4.1756x; 1.1936x over previous
//
#include <hip/hip_runtime.h>
#include <cmath>

#define B_ 2
#define N_ 4096
#define E_ 1024
#define D_ 128
#define H_ 8
#define CHUNK 64
#define NC_ (N_/CHUNK)   // 64

__device__ __forceinline__ float sigmoidf_(float x){ return 1.f/(1.f + __expf(-x)); }

__device__ __forceinline__ unsigned short f2bf(float f){
    unsigned u = __float_as_uint(f);
    u += 0x7FFFu + ((u >> 16) & 1u);      // round-to-nearest-even
    return (unsigned short)(u >> 16);
}
__device__ __forceinline__ float bf2f(unsigned short s){
    return __uint_as_float(((unsigned)s) << 16);
}

typedef __attribute__((ext_vector_type(8))) __bf16 bf16x8;
typedef __attribute__((ext_vector_type(4))) float  f32x4;
typedef __attribute__((address_space(3))) unsigned int as3_u32;
typedef __attribute__((address_space(1))) unsigned int as1_u32;

__device__ __forceinline__ void gload_lds16(const void* g, void* l){
    __builtin_amdgcn_global_load_lds((as1_u32*)g, (as3_u32*)l, 16, 0, 0);
}

// fragment load from LDS tile with 256B rows (128 bf16/row), XOR-swizzled
__device__ __forceinline__ bf16x8 ldsfrag256(const unsigned short* Lp, int row, int kg){
    return *reinterpret_cast<const bf16x8*>(&Lp[row*128 + ((kg ^ (row&7))<<3)]);
}
// fragment load from LDS tile with 128B rows (64 bf16/row)
__device__ __forceinline__ bf16x8 ldsfrag128(const unsigned short* Lp, int row, int kg){
    return *reinterpret_cast<const bf16x8*>(&Lp[row*64 + ((kg ^ (row&7))<<3)]);
}

// ---------------------------------------------------------------------------
// bf16 MFMA GEMM: C[M,N] = A[M,K] @ Bw[N,K]^T.  128x128 tile, BK=64, 4 waves.
// + T1 bijective XCD swizzle (all grids have nwg % 8 == 0).
// ---------------------------------------------------------------------------
template<bool OUT_BF16>
__global__ __launch_bounds__(256) void gemm_bf16(
    const unsigned short* __restrict__ A,
    const unsigned short* __restrict__ Bw,
    void* __restrict__ Cout, int M, int N, int K)
{
    __shared__ unsigned short As[128*64];
    __shared__ unsigned short Bs[128*64];
    const int tid  = threadIdx.x;
    const int wave = tid >> 6;
    const int lane = tid & 63;
    // XCD-aware swizzle (nwg % 8 == 0 for all launches here)
    const int gx = gridDim.x;
    const int nwg = gx * gridDim.y;
    int bid = blockIdx.y*gx + blockIdx.x;
    bid = (bid & 7)*(nwg >> 3) + (bid >> 3);
    const int m0 = (bid / gx) * 128, n0 = (bid % gx) * 128;
    const int wr = (wave >> 1) * 64;
    const int wc = (wave & 1) * 64;
    const int l15 = lane & 15, l4 = lane >> 4;
    const int p = l15 & 7;

    f32x4 acc[4][4];
#pragma unroll
    for (int i=0;i<4;i++)
#pragma unroll
        for (int j=0;j<4;j++)
#pragma unroll
            for (int q=0;q<4;q++) acc[i][j][q]=0.f;

    const int srow = wave*32 + (lane>>3);
    const int sgrp = lane & 7;

    for (int k0=0; k0<K; k0+=64){
        if (k0) __syncthreads();
#pragma unroll
        for (int i=0;i<4;i++){
            const int r  = srow + 8*i;
            const int cg = sgrp ^ (r & 7);
            gload_lds16(A  + (size_t)(m0 + r)*K + k0 + cg*8, &As[(wave*32 + 8*i)*64]);
            gload_lds16(Bw + (size_t)(n0 + r)*K + k0 + cg*8, &Bs[(wave*32 + 8*i)*64]);
        }
        __syncthreads();
#pragma unroll
        for (int ks=0; ks<2; ks++){
            bf16x8 av[4], bv[4];
            const int tA = (((ks<<2) | l4) ^ p) << 3;
#pragma unroll
            for (int f=0; f<4; f++){
                const int rowA = wr + f*16 + l15;
                const int rowB = wc + f*16 + l15;
                av[f] = *reinterpret_cast<const bf16x8*>(&As[(rowA<<6) + tA]);
                bv[f] = *reinterpret_cast<const bf16x8*>(&Bs[(rowB<<6) + tA]);
            }
#pragma unroll
            for (int fm=0; fm<4; fm++)
#pragma unroll
                for (int fn=0; fn<4; fn++)
                    acc[fm][fn] = __builtin_amdgcn_mfma_f32_16x16x32_bf16(
                        av[fm], bv[fn], acc[fm][fn], 0, 0, 0);
        }
    }
    const int crow0 = m0 + wr + l4*4;
    const int ccol0 = n0 + wc + l15;
    if (!OUT_BF16){
        float* C = (float*)Cout;
#pragma unroll
        for (int fm=0; fm<4; fm++)
#pragma unroll
            for (int fn=0; fn<4; fn++)
#pragma unroll
                for (int j=0;j<4;j++)
                    C[(size_t)(crow0 + fm*16 + j)*N + ccol0 + fn*16] = acc[fm][fn][j];
    } else {
        unsigned short* C = (unsigned short*)Cout;
#pragma unroll
        for (int fm=0; fm<4; fm++)
#pragma unroll
            for (int fn=0; fn<4; fn++)
#pragma unroll
                for (int j=0;j<4;j++)
                    C[(size_t)(crow0 + fm*16 + j)*N + ccol0 + fn*16] = f2bf(acc[fm][fn][j]);
    }
}

// ---------------------------------------------------------------------------
__global__ __launch_bounds__(256) void cast_bf16(
    const float* __restrict__ in, unsigned short* __restrict__ out, int n4)
{
    for (int i = blockIdx.x*256 + threadIdx.x; i < n4; i += gridDim.x*256){
        const float4 v = reinterpret_cast<const float4*>(in)[i];
        ushort4 o;
        o.x = f2bf(v.x); o.y = f2bf(v.y); o.z = f2bf(v.z); o.w = f2bf(v.w);
        reinterpret_cast<ushort4*>(out)[i] = o;
    }
}

// ---------------------------------------------------------------------------
// Prep v2: 256 threads = (d 0..127) x (t-half 0..1). Per (b,h,chunk):
//   b_t = prefix of logsigmoid(lg).  Emits bf16:
//   QS[t,d]=silu(q)e^{b_t}; KIN[s,d]=(1-sig)e^{-b_s};
//   KINt[d,s]=KIN*e^{BC_d} (<=1, transposed, from registers);
//   Vt[d,s]=v transposed (from registers).  BC[d] f32.
// LDS: only local-prefix array (34 KB) -> ~4 blocks/CU.
// ---------------------------------------------------------------------------
__global__ __launch_bounds__(256) void gla_prep(
    const float* __restrict__ u, float* __restrict__ BC,
    unsigned short* __restrict__ QSb, unsigned short* __restrict__ KINb,
    unsigned short* __restrict__ KINtb, unsigned short* __restrict__ Vtb)
{
    __shared__ float b_l[CHUNK*132];
    __shared__ float tot[2*128];
    const int bid = blockIdx.x;               // (b*H+h)*NC + c
    const int c  = bid % NC_;
    const int hh = (bid / NC_) % H_;
    const int b  = bid / (NC_*H_);
    const int d  = threadIdx.x & 127;
    const int hf = threadIdx.x >> 7;          // which 32-t half
    const int t0 = hf*32;
    const size_t urow0 = ((size_t)b*N_ + (size_t)c*CHUNK)*(3*E_) + (size_t)hh*D_ + d;

    // phase 1: g = logsigmoid(lg), local prefix into LDS
    float acc = 0.f;
#pragma unroll
    for (int i=0;i<32;i++){
        const int t = t0 + i;
        const float lg = u[urow0 + (size_t)t*(3*E_) + 2*E_];
        const float g  = (lg >= 0.f) ? -log1pf(__expf(-lg))
                                     : (lg - log1pf(__expf(lg)));
        acc += g;
        b_l[t*132 + d] = acc;                 // local prefix within half
    }
    tot[hf*128 + d] = acc;
    __syncthreads();
    const float tot0 = tot[d];
    const float off  = hf ? tot0 : 0.f;
    const float bcv  = tot0 + tot[128 + d];
    if (hf == 0) BC[(size_t)bid*D_ + d] = bcv;
    const float ebc = __expf(bcv);

    // phase 2: outputs; lane keeps transposed rows (fixed d) in registers
    unsigned kin_pk[16], v_pk[16];
    float Bprev = off;
    const size_t obase = (size_t)bid*CHUNK*D_;
#pragma unroll
    for (int i=0;i<32;i++){
        const int t = t0 + i;
        const size_t r = urow0 + (size_t)t*(3*E_);
        const float q  = u[r + E_];
        const float vv = u[r];
        const float Bc = b_l[t*132 + d] + off;
        const float g  = Bc - Bprev;  Bprev = Bc;
        const float kk = 1.f - __expf(g);              // 1 - sigmoid(lg)
        const float qs  = (q * sigmoidf_(q)) * __expf(Bc);
        const float kin = kk * __expf(-Bc);
        QSb [obase + (size_t)t*D_ + d] = f2bf(qs);
        KINb[obase + (size_t)t*D_ + d] = f2bf(kin);
        const unsigned kb = f2bf(kin * ebc);
        const unsigned vb = f2bf(vv);
        if (i & 1){ kin_pk[i>>1] |= kb<<16; v_pk[i>>1] |= vb<<16; }
        else      { kin_pk[i>>1]  = kb;     v_pk[i>>1]  = vb;     }
    }
    const size_t tbase = (size_t)bid*D_*CHUNK + (size_t)d*CHUNK + t0;
#pragma unroll
    for (int j=0;j<4;j++){
        uint4 kq, vq;
        kq.x=kin_pk[4*j]; kq.y=kin_pk[4*j+1]; kq.z=kin_pk[4*j+2]; kq.w=kin_pk[4*j+3];
        vq.x=v_pk[4*j];   vq.y=v_pk[4*j+1];   vq.z=v_pk[4*j+2];   vq.w=v_pk[4*j+3];
        *reinterpret_cast<uint4*>(&KINtb[tbase + j*8]) = kq;
        *reinterpret_cast<uint4*>(&Vtb  [tbase + j*8]) = vq;
    }
}

// ---------------------------------------------------------------------------
// Batched chunk summary (MFMA): McT[bid][e][d] = sum_s Vt[e,s]*KINt[d,s]
// bf16 output (feeds the bf16 scan states anyway).
// ---------------------------------------------------------------------------
__global__ __launch_bounds__(256) void gla_chunk_mm(
    const unsigned short* __restrict__ Vtb,
    const unsigned short* __restrict__ KINtb,
    unsigned short* __restrict__ McTb)
{
    __shared__ unsigned short As[128*64];
    __shared__ unsigned short Bs[128*64];
    const int bid = blockIdx.x;
    const int tid = threadIdx.x;
    const int w = tid >> 6, lane = tid & 63;
    const int l15 = lane & 15, l4 = lane >> 4;
    const int wr = (w >> 1) * 64, wc = (w & 1) * 64;
    const unsigned short* A  = Vtb   + (size_t)bid*128*64;
    const unsigned short* Bp = KINtb + (size_t)bid*128*64;

    f32x4 acc[4][4];
#pragma unroll
    for (int i=0;i<4;i++)
#pragma unroll
        for (int j=0;j<4;j++)
#pragma unroll
            for (int q=0;q<4;q++) acc[i][j][q]=0.f;

#pragma unroll
    for (int i=0;i<4;i++){
        const int r  = w*32 + i*8 + (lane>>3);
        const int gs = (lane&7) ^ (r&7);
        gload_lds16(A  + (size_t)r*64 + gs*8, &As[(w*32+i*8)*64]);
        gload_lds16(Bp + (size_t)r*64 + gs*8, &Bs[(w*32+i*8)*64]);
    }
    __syncthreads();
#pragma unroll
    for (int ks=0; ks<2; ks++){
        bf16x8 av[4], bv[4];
#pragma unroll
        for (int f=0; f<4; f++){
            av[f] = ldsfrag128(As, wr + f*16 + l15, ks*4 + l4);
            bv[f] = ldsfrag128(Bs, wc + f*16 + l15, ks*4 + l4);
        }
#pragma unroll
        for (int fm=0; fm<4; fm++)
#pragma unroll
            for (int fn=0; fn<4; fn++)
                acc[fm][fn] = __builtin_amdgcn_mfma_f32_16x16x32_bf16(
                    av[fm], bv[fn], acc[fm][fn], 0, 0, 0);
    }
    unsigned short* C = McTb + (size_t)bid*128*128;
#pragma unroll
    for (int fm=0; fm<4; fm++)
#pragma unroll
        for (int fn=0; fn<4; fn++)
#pragma unroll
            for (int j=0;j<4;j++)
                C[(size_t)(wr + fm*16 + l4*4 + j)*128 + wc + fn*16 + l15] = f2bf(acc[fm][fn][j]);
}

// ---------------------------------------------------------------------------
// Inter-chunk scan over bf16 McT[e][d]; writes bf16 chunk-START states.
// ---------------------------------------------------------------------------
__global__ __launch_bounds__(256) void gla_scan_chunks(
    const unsigned short* __restrict__ McTb, const float* __restrict__ BC,
    unsigned short* __restrict__ Sb16)
{
    const size_t F = (size_t)blockIdx.x*256 + threadIdx.x;   // < B*H*D*D
    const int bh = (int)(F >> 14);
    const int rem = (int)(F & 16383);
    const int d = rem & 127;
    float S = 0.f;
    for (int c=0;c<NC_;c++){
        const size_t idx = (((size_t)bh*NC_ + c) << 14) + rem;
        const float m = bf2f(McTb[idx]);
        const float dec = __expf(BC[((size_t)bh*NC_ + c)*D_ + d]);
        Sb16[idx] = f2bf(S);
        S = dec*S + m;
    }
}

// ---------------------------------------------------------------------------
// Output (MFMA): per (b,h,chunk):
//   A[t,s] = causal(QS @ KIN^T);  O = A @ Vt^T + QS @ S^T  -> Opre [B,N,E] f32
// ---------------------------------------------------------------------------
__global__ __launch_bounds__(256) void gla_output(
    const unsigned short* __restrict__ QSb,
    const unsigned short* __restrict__ KINb,
    const unsigned short* __restrict__ Vtb,
    const unsigned short* __restrict__ Sb,
    float* __restrict__ Opre)
{
    __shared__ unsigned short QS_l[64*128];
    __shared__ unsigned short KA_l[64*128];   // KIN; first 8KB reused for A
    __shared__ unsigned short Vt_l[128*64];
    __shared__ unsigned short S_l [128*128];
    const int bid = blockIdx.x;
    const int c = bid % NC_;
    const int h = (bid / NC_) % H_;
    const int b = bid / (NC_*H_);
    const int tid = threadIdx.x;
    const int w = tid >> 6, lane = tid & 63;
    const int l15 = lane & 15, l4 = lane >> 4;

    {   // ---- stage (pre-swizzled sources, linear LDS dest) ----
        const unsigned short* q = QSb + (size_t)bid*64*128;
        const unsigned short* k = KINb + (size_t)bid*64*128;
        const unsigned short* v = Vtb + (size_t)bid*128*64;
        const unsigned short* s = Sb  + (size_t)bid*128*128;
#pragma unroll
        for (int i=0;i<4;i++){
            const int r  = w*16 + i*4 + (lane>>4);
            const int gs = (lane&15) ^ (r&7);
            gload_lds16(q + (size_t)r*128 + gs*8, &QS_l[(w*16+i*4)*128]);
            gload_lds16(k + (size_t)r*128 + gs*8, &KA_l[(w*16+i*4)*128]);
        }
#pragma unroll
        for (int i=0;i<4;i++){
            const int r  = w*32 + i*8 + (lane>>3);
            const int gs = (lane&7) ^ (r&7);
            gload_lds16(v + (size_t)r*64 + gs*8, &Vt_l[(w*32+i*8)*64]);
        }
#pragma unroll
        for (int i=0;i<8;i++){
            const int r  = w*32 + i*4 + (lane>>4);
            const int gs = (lane&15) ^ (r&7);
            gload_lds16(s + (size_t)r*128 + gs*8, &S_l[(w*32+i*4)*128]);
        }
    }
    __syncthreads();

    // ---- phase A: A[t, w*16 + l15] ----
    f32x4 accA[4];
#pragma unroll
    for (int i=0;i<4;i++)
#pragma unroll
        for (int q=0;q<4;q++) accA[i][q]=0.f;
    const int srow = w*16 + l15;
#pragma unroll
    for (int ks=0; ks<4; ks++){
        const bf16x8 bv = ldsfrag256(KA_l, srow, ks*4 + l4);
#pragma unroll
        for (int ft=0; ft<4; ft++){
            const bf16x8 av = ldsfrag256(QS_l, ft*16 + l15, ks*4 + l4);
            accA[ft] = __builtin_amdgcn_mfma_f32_16x16x32_bf16(av, bv, accA[ft], 0,0,0);
        }
    }
    __syncthreads();            // all KIN reads done before A overwrite
#pragma unroll
    for (int ft=0; ft<4; ft++)
#pragma unroll
        for (int j=0;j<4;j++){
            const int t = ft*16 + l4*4 + j;
            const int s = w*16 + l15;
            const float vA = (t >= s) ? accA[ft][j] : 0.f;
            KA_l[t*64 + (((s>>3) ^ (t&7))<<3) + (s&7)] = f2bf(vA);
        }
    __syncthreads();

    // ---- phase B: O[t, e-slab w] = A @ Vt^T + QS @ S^T ----
    f32x4 acc[4][2];
#pragma unroll
    for (int i=0;i<4;i++)
#pragma unroll
        for (int j=0;j<2;j++)
#pragma unroll
            for (int q=0;q<4;q++) acc[i][j][q]=0.f;
#pragma unroll
    for (int ks=0; ks<2; ks++){                 // O1: K = s = 64
        bf16x8 bv[2];
        bv[0] = ldsfrag128(Vt_l, w*32 +      l15, ks*4 + l4);
        bv[1] = ldsfrag128(Vt_l, w*32 + 16 + l15, ks*4 + l4);
#pragma unroll
        for (int ft=0; ft<4; ft++){
            const bf16x8 av = ldsfrag128(KA_l, ft*16 + l15, ks*4 + l4);
            acc[ft][0] = __builtin_amdgcn_mfma_f32_16x16x32_bf16(av, bv[0], acc[ft][0], 0,0,0);
            acc[ft][1] = __builtin_amdgcn_mfma_f32_16x16x32_bf16(av, bv[1], acc[ft][1], 0,0,0);
        }
    }
#pragma unroll
    for (int ks=0; ks<4; ks++){                 // O2: K = d = 128
        bf16x8 bv[2];
        bv[0] = ldsfrag256(S_l, w*32 +      l15, ks*4 + l4);
        bv[1] = ldsfrag256(S_l, w*32 + 16 + l15, ks*4 + l4);
#pragma unroll
        for (int ft=0; ft<4; ft++){
            const bf16x8 av = ldsfrag256(QS_l, ft*16 + l15, ks*4 + l4);
            acc[ft][0] = __builtin_amdgcn_mfma_f32_16x16x32_bf16(av, bv[0], acc[ft][0], 0,0,0);
            acc[ft][1] = __builtin_amdgcn_mfma_f32_16x16x32_bf16(av, bv[1], acc[ft][1], 0,0,0);
        }
    }
    const size_t rowbase = (size_t)b*N_ + (size_t)c*CHUNK;
#pragma unroll
    for (int ft=0; ft<4; ft++)
#pragma unroll
        for (int fe=0; fe<2; fe++)
#pragma unroll
            for (int j=0;j<4;j++){
                const int t = ft*16 + l4*4 + j;
                const int e = w*32 + fe*16 + l15;
                Opre[(rowbase + t)*E_ + h*D_ + e] = acc[ft][fe][j];
            }
}

// ---------------------------------------------------------------------------
// Gate (sigmoid of bf16 low-rank proj) + LayerNorm -> bf16
// ---------------------------------------------------------------------------
__global__ __launch_bounds__(256) void gate_ln_bf16(
    const float* __restrict__ O, const unsigned short* __restrict__ G2,
    const float* __restrict__ lnw, unsigned short* __restrict__ Ob)
{
    const int row = blockIdx.x;
    const int tid = threadIdx.x;
    const size_t off = (size_t)row*E_ + tid*4;
    float4 o = *reinterpret_cast<const float4*>(&O[off]);
    const ushort4 gu = *reinterpret_cast<const ushort4*>(&G2[off]);
    o.x *= sigmoidf_(bf2f(gu.x)); o.y *= sigmoidf_(bf2f(gu.y));
    o.z *= sigmoidf_(bf2f(gu.z)); o.w *= sigmoidf_(bf2f(gu.w));
    float s1 = o.x+o.y+o.z+o.w;
    float s2 = o.x*o.x + o.y*o.y + o.z*o.z + o.w*o.w;
#pragma unroll
    for (int sh=32; sh>0; sh>>=1){
        s1 += __shfl_down(s1, sh);
        s2 += __shfl_down(s2, sh);
    }
    __shared__ float r1[4], r2[4];
    const int wid = tid >> 6;
    if ((tid & 63)==0){ r1[wid]=s1; r2[wid]=s2; }
    __syncthreads();
    s1 = r1[0]+r1[1]+r1[2]+r1[3];
    s2 = r2[0]+r2[1]+r2[2]+r2[3];
    const float mean = s1 * (1.f/E_);
    const float var  = s2 * (1.f/E_) - mean*mean;
    const float rs   = rsqrtf(var + 1e-5f);
    const float4 w = *reinterpret_cast<const float4*>(&lnw[tid*4]);
    ushort4 r;
    r.x = f2bf((o.x-mean)*rs*w.x); r.y = f2bf((o.y-mean)*rs*w.y);
    r.z = f2bf((o.z-mean)*rs*w.z); r.w = f2bf((o.w-mean)*rs*w.w);
    *reinterpret_cast<ushort4*>(&Ob[off]) = r;
}

// ---------------------------------------------------------------------------
extern "C" void kernel_launch(void* const* d_in, const int* in_sizes, int n_in,
                              void* d_out, int out_size, void* d_ws, size_t ws_size,
                              hipStream_t stream)
{
    const float* x     = (const float*)d_in[0];
    const float* W_in  = (const float*)d_in[1];
    const float* W_out = (const float*)d_in[2];
    const float* W_g1  = (const float*)d_in[3];
    const float* W_g2  = (const float*)d_in[4];
    const float* lnw   = (const float*)d_in[5];
    float* out = (float*)d_out;
    char* ws = (char*)d_ws;

    // workspace layout (bytes); total 246,415,360 (< 256 MiB)
    float*          u      = (float*)(ws);                      // [B,N,3E] f32 (dead after prep); reused:
    unsigned short* McTb   = (unsigned short*)(ws);             //   [B,H,NC,D,D] bf16 33,554,432
    unsigned short* Sb16   = (unsigned short*)(ws + 33554432);  //   [B,H,NC,D,D] bf16 33,554,432
    float*          BC     = (float*)(ws + 100663296);          //       524,288
    unsigned short* QSb    = (unsigned short*)(ws + 101187584); //    16,777,216
    unsigned short* KINb   = (unsigned short*)(ws + 117964800); //    16,777,216
    unsigned short* KINtb  = (unsigned short*)(ws + 134742016); //    16,777,216
    unsigned short* Vtb    = (unsigned short*)(ws + 151519232); //    16,777,216
    float*          Opre   = (float*)(ws + 168296448);          //    33,554,432
    unsigned short* xb     = (unsigned short*)(ws + 201850880); //    16,777,216
    unsigned short* W_inb  = (unsigned short*)(ws + 218628096); //     6,291,456
    unsigned short* W_outb = (unsigned short*)(ws + 224919552); //     2,097,152
    unsigned short* W_g1b  = (unsigned short*)(ws + 227016704); //       262,144
    unsigned short* W_g2b  = (unsigned short*)(ws + 227278848); //       262,144
    unsigned short* G1b    = (unsigned short*)(ws + 227540992); //     2,097,152
    unsigned short* ObF    = (unsigned short*)(ws + 229638144); //    16,777,216
    unsigned short* G2b    = QSb;   // reuse QSb (dead after gla_output)

    const int M = B_*N_;     // 8192
    dim3 blk(256);

    // casts to bf16
    cast_bf16<<<2048, blk, 0, stream>>>(x,     xb,     (B_*N_*E_)/4);
    cast_bf16<<<2048, blk, 0, stream>>>(W_in,  W_inb,  (3*E_*E_)/4);
    cast_bf16<<<1024, blk, 0, stream>>>(W_out, W_outb, (E_*E_)/4);
    cast_bf16<<<128,  blk, 0, stream>>>(W_g1,  W_g1b,  (D_*E_)/4);
    cast_bf16<<<128,  blk, 0, stream>>>(W_g2,  W_g2b,  (E_*D_)/4);

    // 1) u = x @ W_in^T  (f32 out)
    gemm_bf16<false><<<dim3(3*E_/128, M/128), blk, 0, stream>>>(xb, W_inb, u, M, 3*E_, E_);
    // 2) prep: bf16 QS/KIN + register-transposed KINt/Vt + BC  (u dead after)
    gla_prep<<<dim3(B_*H_*NC_), blk, 0, stream>>>(u, BC, QSb, KINb, KINtb, Vtb);
    // 3) per-chunk summaries McT[e][d] (MFMA, bf16 out) into old u region
    gla_chunk_mm<<<dim3(B_*H_*NC_), blk, 0, stream>>>(Vtb, KINtb, McTb);
    // 4) inter-chunk scan -> bf16 start states
    gla_scan_chunks<<<dim3((B_*H_*D_*D_)/256), blk, 0, stream>>>(McTb, BC, Sb16);
    // 5) per-chunk outputs (MFMA)
    gla_output<<<dim3(B_*H_*NC_), blk, 0, stream>>>(QSb, KINb, Vtb, Sb16, Opre);
    // 6) G1 = x @ W_g1^T  (bf16 out)
    gemm_bf16<true><<<dim3(1, M/128), blk, 0, stream>>>(xb, W_g1b, G1b, M, D_, E_);
    // 7) G2 = G1 @ W_g2^T (bf16 out, over dead QSb)
    gemm_bf16<true><<<dim3(E_/128, M/128), blk, 0, stream>>>(G1b, W_g2b, G2b, M, E_, D_);
    // 8) gate + layernorm -> bf16
    gate_ln_bf16<<<dim3(M), blk, 0, stream>>>(Opre, G2b, lnw, ObF);
    // 9) out = LN(o) @ W_out^T
    gemm_bf16<false><<<dim3(E_/128, M/128), blk, 0, stream>>>(ObF, W_outb, out, M, E_, E_);
}

// Round 6
// 261.426 us; speedup vs baseline: 4.5374x; 1.0866x over previous
//
#include <hip/hip_runtime.h>
#include <cmath>

#define B_ 2
#define N_ 4096
#define E_ 1024
#define D_ 128
#define H_ 8
#define CHUNK 64
#define NC_ (N_/CHUNK)   // 64

__device__ __forceinline__ float sigmoidf_(float x){ return 1.f/(1.f + __expf(-x)); }

__device__ __forceinline__ unsigned short f2bf(float f){
    unsigned u = __float_as_uint(f);
    u += 0x7FFFu + ((u >> 16) & 1u);      // round-to-nearest-even
    return (unsigned short)(u >> 16);
}
__device__ __forceinline__ float bf2f(unsigned short s){
    return __uint_as_float(((unsigned)s) << 16);
}

typedef __attribute__((ext_vector_type(8))) __bf16 bf16x8;
typedef __attribute__((ext_vector_type(4))) float  f32x4;
typedef __attribute__((address_space(3))) unsigned int as3_u32;
typedef __attribute__((address_space(1))) unsigned int as1_u32;

__device__ __forceinline__ void gload_lds16(const void* g, void* l){
    __builtin_amdgcn_global_load_lds((as1_u32*)g, (as3_u32*)l, 16, 0, 0);
}

// fragment load from LDS tile with 256B rows (128 bf16/row), XOR-swizzled
__device__ __forceinline__ bf16x8 ldsfrag256(const unsigned short* Lp, int row, int kg){
    return *reinterpret_cast<const bf16x8*>(&Lp[row*128 + ((kg ^ (row&7))<<3)]);
}
// fragment load from LDS tile with 128B rows (64 bf16/row)
__device__ __forceinline__ bf16x8 ldsfrag128(const unsigned short* Lp, int row, int kg){
    return *reinterpret_cast<const bf16x8*>(&Lp[row*64 + ((kg ^ (row&7))<<3)]);
}

// ---------------------------------------------------------------------------
// bf16 MFMA GEMM: C[M,N] = A[M,K] @ Bw[N,K]^T.  128x128 tile, BK=64, 4 waves.
// + T1 bijective XCD swizzle (all grids have nwg % 8 == 0).
// ---------------------------------------------------------------------------
template<bool OUT_BF16>
__global__ __launch_bounds__(256) void gemm_bf16(
    const unsigned short* __restrict__ A,
    const unsigned short* __restrict__ Bw,
    void* __restrict__ Cout, int M, int N, int K)
{
    __shared__ unsigned short As[128*64];
    __shared__ unsigned short Bs[128*64];
    const int tid  = threadIdx.x;
    const int wave = tid >> 6;
    const int lane = tid & 63;
    const int gx = gridDim.x;
    const int nwg = gx * gridDim.y;
    int bid = blockIdx.y*gx + blockIdx.x;
    bid = (bid & 7)*(nwg >> 3) + (bid >> 3);
    const int m0 = (bid / gx) * 128, n0 = (bid % gx) * 128;
    const int wr = (wave >> 1) * 64;
    const int wc = (wave & 1) * 64;
    const int l15 = lane & 15, l4 = lane >> 4;
    const int p = l15 & 7;

    f32x4 acc[4][4];
#pragma unroll
    for (int i=0;i<4;i++)
#pragma unroll
        for (int j=0;j<4;j++)
#pragma unroll
            for (int q=0;q<4;q++) acc[i][j][q]=0.f;

    const int srow = wave*32 + (lane>>3);
    const int sgrp = lane & 7;

    for (int k0=0; k0<K; k0+=64){
        if (k0) __syncthreads();
#pragma unroll
        for (int i=0;i<4;i++){
            const int r  = srow + 8*i;
            const int cg = sgrp ^ (r & 7);
            gload_lds16(A  + (size_t)(m0 + r)*K + k0 + cg*8, &As[(wave*32 + 8*i)*64]);
            gload_lds16(Bw + (size_t)(n0 + r)*K + k0 + cg*8, &Bs[(wave*32 + 8*i)*64]);
        }
        __syncthreads();
#pragma unroll
        for (int ks=0; ks<2; ks++){
            bf16x8 av[4], bv[4];
            const int tA = (((ks<<2) | l4) ^ p) << 3;
#pragma unroll
            for (int f=0; f<4; f++){
                const int rowA = wr + f*16 + l15;
                const int rowB = wc + f*16 + l15;
                av[f] = *reinterpret_cast<const bf16x8*>(&As[(rowA<<6) + tA]);
                bv[f] = *reinterpret_cast<const bf16x8*>(&Bs[(rowB<<6) + tA]);
            }
#pragma unroll
            for (int fm=0; fm<4; fm++)
#pragma unroll
                for (int fn=0; fn<4; fn++)
                    acc[fm][fn] = __builtin_amdgcn_mfma_f32_16x16x32_bf16(
                        av[fm], bv[fn], acc[fm][fn], 0, 0, 0);
        }
    }
    const int crow0 = m0 + wr + l4*4;
    const int ccol0 = n0 + wc + l15;
    if (!OUT_BF16){
        float* C = (float*)Cout;
#pragma unroll
        for (int fm=0; fm<4; fm++)
#pragma unroll
            for (int fn=0; fn<4; fn++)
#pragma unroll
                for (int j=0;j<4;j++)
                    C[(size_t)(crow0 + fm*16 + j)*N + ccol0 + fn*16] = acc[fm][fn][j];
    } else {
        unsigned short* C = (unsigned short*)Cout;
#pragma unroll
        for (int fm=0; fm<4; fm++)
#pragma unroll
            for (int fn=0; fn<4; fn++)
#pragma unroll
                for (int j=0;j<4;j++)
                    C[(size_t)(crow0 + fm*16 + j)*N + ccol0 + fn*16] = f2bf(acc[fm][fn][j]);
    }
}

// ---------------------------------------------------------------------------
__global__ __launch_bounds__(256) void cast_bf16(
    const float* __restrict__ in, unsigned short* __restrict__ out, int n4)
{
    for (int i = blockIdx.x*256 + threadIdx.x; i < n4; i += gridDim.x*256){
        const float4 v = reinterpret_cast<const float4*>(in)[i];
        ushort4 o;
        o.x = f2bf(v.x); o.y = f2bf(v.y); o.z = f2bf(v.z); o.w = f2bf(v.w);
        reinterpret_cast<ushort4*>(out)[i] = o;
    }
}

// ---------------------------------------------------------------------------
// Prep v3: u is bf16. 256 threads = (d 0..127) x (t-half 0..1).
// All 96 loads issued up front; prefix kept in registers; LDS = 1KB (tot).
// Emits bf16 QS/KIN (row-major) + KINt/Vt (transposed, from registers) + BC.
// ---------------------------------------------------------------------------
__global__ __launch_bounds__(256) void gla_prep(
    const unsigned short* __restrict__ u, float* __restrict__ BC,
    unsigned short* __restrict__ QSb, unsigned short* __restrict__ KINb,
    unsigned short* __restrict__ KINtb, unsigned short* __restrict__ Vtb)
{
    __shared__ float tot[2*128];
    const int bid = blockIdx.x;               // (b*H+h)*NC + c
    const int c  = bid % NC_;
    const int hh = (bid / NC_) % H_;
    const int b  = bid / (NC_*H_);
    const int d  = threadIdx.x & 127;
    const int hf = threadIdx.x >> 7;          // which 32-t half
    const int t0 = hf*32;
    const size_t urow0 = ((size_t)b*N_ + (size_t)c*CHUNK)*(3*E_) + (size_t)hh*D_ + d;

    // issue everything up front (independent); lg first (needed first)
    float bl[32], qv[32], vv[32];
#pragma unroll
    for (int i=0;i<32;i++)
        bl[i] = bf2f(u[urow0 + (size_t)(t0+i)*(3*E_) + 2*E_]);   // lg
#pragma unroll
    for (int i=0;i<32;i++)
        qv[i] = bf2f(u[urow0 + (size_t)(t0+i)*(3*E_) + E_]);     // q
#pragma unroll
    for (int i=0;i<32;i++)
        vv[i] = bf2f(u[urow0 + (size_t)(t0+i)*(3*E_)]);          // v

    // phase 1: local prefix of logsigmoid in registers
    float acc = 0.f;
#pragma unroll
    for (int i=0;i<32;i++){
        const float lg = bl[i];
        const float g  = (lg >= 0.f) ? -log1pf(__expf(-lg))
                                     : (lg - log1pf(__expf(lg)));
        acc += g;
        bl[i] = acc;
    }
    tot[hf*128 + d] = acc;
    __syncthreads();
    const float tot0 = tot[d];
    const float off  = hf ? tot0 : 0.f;
    const float bcv  = tot0 + tot[128 + d];
    if (hf == 0) BC[(size_t)bid*D_ + d] = bcv;

    // phase 2: compute + store (q/v already in registers)
    unsigned kin_pk[16], v_pk[16];
    float prev = 0.f;
    const size_t obase = (size_t)bid*CHUNK*D_;
#pragma unroll
    for (int i=0;i<32;i++){
        const int t = t0 + i;
        const float Bl = bl[i];
        const float g  = Bl - prev;  prev = Bl;        // local diff, off cancels
        const float Bc = Bl + off;
        const float kk = 1.f - __expf(g);              // 1 - sigmoid(lg)
        const float q  = qv[i];
        const float qs  = (q * sigmoidf_(q)) * __expf(Bc);
        const float kin = kk * __expf(-Bc);
        QSb [obase + (size_t)t*D_ + d] = f2bf(qs);
        KINb[obase + (size_t)t*D_ + d] = f2bf(kin);
        const unsigned kb = f2bf(kk * __expf(bcv - Bc));   // KIN * e^{BC_d}  (<=1)
        const unsigned vb = f2bf(vv[i]);
        if (i & 1){ kin_pk[i>>1] |= kb<<16; v_pk[i>>1] |= vb<<16; }
        else      { kin_pk[i>>1]  = kb;     v_pk[i>>1]  = vb;     }
    }
    const size_t tbase = (size_t)bid*D_*CHUNK + (size_t)d*CHUNK + t0;
#pragma unroll
    for (int j=0;j<4;j++){
        uint4 kq, vq;
        kq.x=kin_pk[4*j]; kq.y=kin_pk[4*j+1]; kq.z=kin_pk[4*j+2]; kq.w=kin_pk[4*j+3];
        vq.x=v_pk[4*j];   vq.y=v_pk[4*j+1];   vq.z=v_pk[4*j+2];   vq.w=v_pk[4*j+3];
        *reinterpret_cast<uint4*>(&KINtb[tbase + j*8]) = kq;
        *reinterpret_cast<uint4*>(&Vtb  [tbase + j*8]) = vq;
    }
}

// ---------------------------------------------------------------------------
// Batched chunk summary (MFMA): McT[bid][e][d] = sum_s Vt[e,s]*KINt[d,s]
// ---------------------------------------------------------------------------
__global__ __launch_bounds__(256) void gla_chunk_mm(
    const unsigned short* __restrict__ Vtb,
    const unsigned short* __restrict__ KINtb,
    unsigned short* __restrict__ McTb)
{
    __shared__ unsigned short As[128*64];
    __shared__ unsigned short Bs[128*64];
    const int bid = blockIdx.x;
    const int tid = threadIdx.x;
    const int w = tid >> 6, lane = tid & 63;
    const int l15 = lane & 15, l4 = lane >> 4;
    const int wr = (w >> 1) * 64, wc = (w & 1) * 64;
    const unsigned short* A  = Vtb   + (size_t)bid*128*64;
    const unsigned short* Bp = KINtb + (size_t)bid*128*64;

    f32x4 acc[4][4];
#pragma unroll
    for (int i=0;i<4;i++)
#pragma unroll
        for (int j=0;j<4;j++)
#pragma unroll
            for (int q=0;q<4;q++) acc[i][j][q]=0.f;

#pragma unroll
    for (int i=0;i<4;i++){
        const int r  = w*32 + i*8 + (lane>>3);
        const int gs = (lane&7) ^ (r&7);
        gload_lds16(A  + (size_t)r*64 + gs*8, &As[(w*32+i*8)*64]);
        gload_lds16(Bp + (size_t)r*64 + gs*8, &Bs[(w*32+i*8)*64]);
    }
    __syncthreads();
#pragma unroll
    for (int ks=0; ks<2; ks++){
        bf16x8 av[4], bv[4];
#pragma unroll
        for (int f=0; f<4; f++){
            av[f] = ldsfrag128(As, wr + f*16 + l15, ks*4 + l4);
            bv[f] = ldsfrag128(Bs, wc + f*16 + l15, ks*4 + l4);
        }
#pragma unroll
        for (int fm=0; fm<4; fm++)
#pragma unroll
            for (int fn=0; fn<4; fn++)
                acc[fm][fn] = __builtin_amdgcn_mfma_f32_16x16x32_bf16(
                    av[fm], bv[fn], acc[fm][fn], 0, 0, 0);
    }
    unsigned short* C = McTb + (size_t)bid*128*128;
#pragma unroll
    for (int fm=0; fm<4; fm++)
#pragma unroll
        for (int fn=0; fn<4; fn++)
#pragma unroll
            for (int j=0;j<4;j++)
                C[(size_t)(wr + fm*16 + l4*4 + j)*128 + wc + fn*16 + l15] = f2bf(acc[fm][fn][j]);
}

// ---------------------------------------------------------------------------
// Inter-chunk scan over bf16 McT[e][d]; writes bf16 chunk-START states.
// ---------------------------------------------------------------------------
__global__ __launch_bounds__(256) void gla_scan_chunks(
    const unsigned short* __restrict__ McTb, const float* __restrict__ BC,
    unsigned short* __restrict__ Sb16)
{
    const size_t F = (size_t)blockIdx.x*256 + threadIdx.x;   // < B*H*D*D
    const int bh = (int)(F >> 14);
    const int rem = (int)(F & 16383);
    const int d = rem & 127;
    float S = 0.f;
    for (int c=0;c<NC_;c++){
        const size_t idx = (((size_t)bh*NC_ + c) << 14) + rem;
        const float m = bf2f(McTb[idx]);
        const float dec = __expf(BC[((size_t)bh*NC_ + c)*D_ + d]);
        Sb16[idx] = f2bf(S);
        S = dec*S + m;
    }
}

// ---------------------------------------------------------------------------
// Output (MFMA): per (b,h,chunk):
//   A[t,s] = causal(QS @ KIN^T);  O = A @ Vt^T + QS @ S^T  -> Opre [B,N,E] f32
// ---------------------------------------------------------------------------
__global__ __launch_bounds__(256) void gla_output(
    const unsigned short* __restrict__ QSb,
    const unsigned short* __restrict__ KINb,
    const unsigned short* __restrict__ Vtb,
    const unsigned short* __restrict__ Sb,
    float* __restrict__ Opre)
{
    __shared__ unsigned short QS_l[64*128];
    __shared__ unsigned short KA_l[64*128];   // KIN; first 8KB reused for A
    __shared__ unsigned short Vt_l[128*64];
    __shared__ unsigned short S_l [128*128];
    const int bid = blockIdx.x;
    const int c = bid % NC_;
    const int h = (bid / NC_) % H_;
    const int b = bid / (NC_*H_);
    const int tid = threadIdx.x;
    const int w = tid >> 6, lane = tid & 63;
    const int l15 = lane & 15, l4 = lane >> 4;

    {   // ---- stage (pre-swizzled sources, linear LDS dest) ----
        const unsigned short* q = QSb + (size_t)bid*64*128;
        const unsigned short* k = KINb + (size_t)bid*64*128;
        const unsigned short* v = Vtb + (size_t)bid*128*64;
        const unsigned short* s = Sb  + (size_t)bid*128*128;
#pragma unroll
        for (int i=0;i<4;i++){
            const int r  = w*16 + i*4 + (lane>>4);
            const int gs = (lane&15) ^ (r&7);
            gload_lds16(q + (size_t)r*128 + gs*8, &QS_l[(w*16+i*4)*128]);
            gload_lds16(k + (size_t)r*128 + gs*8, &KA_l[(w*16+i*4)*128]);
        }
#pragma unroll
        for (int i=0;i<4;i++){
            const int r  = w*32 + i*8 + (lane>>3);
            const int gs = (lane&7) ^ (r&7);
            gload_lds16(v + (size_t)r*64 + gs*8, &Vt_l[(w*32+i*8)*64]);
        }
#pragma unroll
        for (int i=0;i<8;i++){
            const int r  = w*32 + i*4 + (lane>>4);
            const int gs = (lane&15) ^ (r&7);
            gload_lds16(s + (size_t)r*128 + gs*8, &S_l[(w*32+i*4)*128]);
        }
    }
    __syncthreads();

    // ---- phase A: A[t, w*16 + l15] ----
    f32x4 accA[4];
#pragma unroll
    for (int i=0;i<4;i++)
#pragma unroll
        for (int q=0;q<4;q++) accA[i][q]=0.f;
    const int srow = w*16 + l15;
#pragma unroll
    for (int ks=0; ks<4; ks++){
        const bf16x8 bv = ldsfrag256(KA_l, srow, ks*4 + l4);
#pragma unroll
        for (int ft=0; ft<4; ft++){
            const bf16x8 av = ldsfrag256(QS_l, ft*16 + l15, ks*4 + l4);
            accA[ft] = __builtin_amdgcn_mfma_f32_16x16x32_bf16(av, bv, accA[ft], 0,0,0);
        }
    }
    __syncthreads();            // all KIN reads done before A overwrite
#pragma unroll
    for (int ft=0; ft<4; ft++)
#pragma unroll
        for (int j=0;j<4;j++){
            const int t = ft*16 + l4*4 + j;
            const int s = w*16 + l15;
            const float vA = (t >= s) ? accA[ft][j] : 0.f;
            KA_l[t*64 + (((s>>3) ^ (t&7))<<3) + (s&7)] = f2bf(vA);
        }
    __syncthreads();

    // ---- phase B: O[t, e-slab w] = A @ Vt^T + QS @ S^T ----
    f32x4 acc[4][2];
#pragma unroll
    for (int i=0;i<4;i++)
#pragma unroll
        for (int j=0;j<2;j++)
#pragma unroll
            for (int q=0;q<4;q++) acc[i][j][q]=0.f;
#pragma unroll
    for (int ks=0; ks<2; ks++){                 // O1: K = s = 64
        bf16x8 bv[2];
        bv[0] = ldsfrag128(Vt_l, w*32 +      l15, ks*4 + l4);
        bv[1] = ldsfrag128(Vt_l, w*32 + 16 + l15, ks*4 + l4);
#pragma unroll
        for (int ft=0; ft<4; ft++){
            const bf16x8 av = ldsfrag128(KA_l, ft*16 + l15, ks*4 + l4);
            acc[ft][0] = __builtin_amdgcn_mfma_f32_16x16x32_bf16(av, bv[0], acc[ft][0], 0,0,0);
            acc[ft][1] = __builtin_amdgcn_mfma_f32_16x16x32_bf16(av, bv[1], acc[ft][1], 0,0,0);
        }
    }
#pragma unroll
    for (int ks=0; ks<4; ks++){                 // O2: K = d = 128
        bf16x8 bv[2];
        bv[0] = ldsfrag256(S_l, w*32 +      l15, ks*4 + l4);
        bv[1] = ldsfrag256(S_l, w*32 + 16 + l15, ks*4 + l4);
#pragma unroll
        for (int ft=0; ft<4; ft++){
            const bf16x8 av = ldsfrag256(QS_l, ft*16 + l15, ks*4 + l4);
            acc[ft][0] = __builtin_amdgcn_mfma_f32_16x16x32_bf16(av, bv[0], acc[ft][0], 0,0,0);
            acc[ft][1] = __builtin_amdgcn_mfma_f32_16x16x32_bf16(av, bv[1], acc[ft][1], 0,0,0);
        }
    }
    const size_t rowbase = (size_t)b*N_ + (size_t)c*CHUNK;
#pragma unroll
    for (int ft=0; ft<4; ft++)
#pragma unroll
        for (int fe=0; fe<2; fe++)
#pragma unroll
            for (int j=0;j<4;j++){
                const int t = ft*16 + l4*4 + j;
                const int e = w*32 + fe*16 + l15;
                Opre[(rowbase + t)*E_ + h*D_ + e] = acc[ft][fe][j];
            }
}

// ---------------------------------------------------------------------------
// Gate (sigmoid of bf16 low-rank proj) + LayerNorm -> bf16
// ---------------------------------------------------------------------------
__global__ __launch_bounds__(256) void gate_ln_bf16(
    const float* __restrict__ O, const unsigned short* __restrict__ G2,
    const float* __restrict__ lnw, unsigned short* __restrict__ Ob)
{
    const int row = blockIdx.x;
    const int tid = threadIdx.x;
    const size_t off = (size_t)row*E_ + tid*4;
    float4 o = *reinterpret_cast<const float4*>(&O[off]);
    const ushort4 gu = *reinterpret_cast<const ushort4*>(&G2[off]);
    o.x *= sigmoidf_(bf2f(gu.x)); o.y *= sigmoidf_(bf2f(gu.y));
    o.z *= sigmoidf_(bf2f(gu.z)); o.w *= sigmoidf_(bf2f(gu.w));
    float s1 = o.x+o.y+o.z+o.w;
    float s2 = o.x*o.x + o.y*o.y + o.z*o.z + o.w*o.w;
#pragma unroll
    for (int sh=32; sh>0; sh>>=1){
        s1 += __shfl_down(s1, sh);
        s2 += __shfl_down(s2, sh);
    }
    __shared__ float r1[4], r2[4];
    const int wid = tid >> 6;
    if ((tid & 63)==0){ r1[wid]=s1; r2[wid]=s2; }
    __syncthreads();
    s1 = r1[0]+r1[1]+r1[2]+r1[3];
    s2 = r2[0]+r2[1]+r2[2]+r2[3];
    const float mean = s1 * (1.f/E_);
    const float var  = s2 * (1.f/E_) - mean*mean;
    const float rs   = rsqrtf(var + 1e-5f);
    const float4 w = *reinterpret_cast<const float4*>(&lnw[tid*4]);
    ushort4 r;
    r.x = f2bf((o.x-mean)*rs*w.x); r.y = f2bf((o.y-mean)*rs*w.y);
    r.z = f2bf((o.z-mean)*rs*w.z); r.w = f2bf((o.w-mean)*rs*w.w);
    *reinterpret_cast<ushort4*>(&Ob[off]) = r;
}

// ---------------------------------------------------------------------------
extern "C" void kernel_launch(void* const* d_in, const int* in_sizes, int n_in,
                              void* d_out, int out_size, void* d_ws, size_t ws_size,
                              hipStream_t stream)
{
    const float* x     = (const float*)d_in[0];
    const float* W_in  = (const float*)d_in[1];
    const float* W_out = (const float*)d_in[2];
    const float* W_g1  = (const float*)d_in[3];
    const float* W_g2  = (const float*)d_in[4];
    const float* lnw   = (const float*)d_in[5];
    float* out = (float*)d_out;
    char* ws = (char*)d_ws;

    // workspace layout (bytes); total 246,415,360 (< 256 MiB)
    unsigned short* ub     = (unsigned short*)(ws);             // [B,N,3E] bf16 50,331,648 (dead after prep); reused:
    unsigned short* McTb   = (unsigned short*)(ws);             //   [B,H,NC,D,D] bf16 33,554,432
    unsigned short* Sb16   = (unsigned short*)(ws + 33554432);  //   [B,H,NC,D,D] bf16 33,554,432
    float*          BC     = (float*)(ws + 100663296);          //       524,288
    unsigned short* QSb    = (unsigned short*)(ws + 101187584); //    16,777,216
    unsigned short* KINb   = (unsigned short*)(ws + 117964800); //    16,777,216
    unsigned short* KINtb  = (unsigned short*)(ws + 134742016); //    16,777,216
    unsigned short* Vtb    = (unsigned short*)(ws + 151519232); //    16,777,216
    float*          Opre   = (float*)(ws + 168296448);          //    33,554,432
    unsigned short* xb     = (unsigned short*)(ws + 201850880); //    16,777,216
    unsigned short* W_inb  = (unsigned short*)(ws + 218628096); //     6,291,456
    unsigned short* W_outb = (unsigned short*)(ws + 224919552); //     2,097,152
    unsigned short* W_g1b  = (unsigned short*)(ws + 227016704); //       262,144
    unsigned short* W_g2b  = (unsigned short*)(ws + 227278848); //       262,144
    unsigned short* G1b    = (unsigned short*)(ws + 227540992); //     2,097,152
    unsigned short* ObF    = (unsigned short*)(ws + 229638144); //    16,777,216
    unsigned short* G2b    = QSb;   // reuse QSb (dead after gla_output)

    const int M = B_*N_;     // 8192
    dim3 blk(256);

    // casts to bf16
    cast_bf16<<<2048, blk, 0, stream>>>(x,     xb,     (B_*N_*E_)/4);
    cast_bf16<<<2048, blk, 0, stream>>>(W_in,  W_inb,  (3*E_*E_)/4);
    cast_bf16<<<1024, blk, 0, stream>>>(W_out, W_outb, (E_*E_)/4);
    cast_bf16<<<128,  blk, 0, stream>>>(W_g1,  W_g1b,  (D_*E_)/4);
    cast_bf16<<<128,  blk, 0, stream>>>(W_g2,  W_g2b,  (E_*D_)/4);

    // 1) u = x @ W_in^T  (bf16 out)
    gemm_bf16<true><<<dim3(3*E_/128, M/128), blk, 0, stream>>>(xb, W_inb, ub, M, 3*E_, E_);
    // 2) prep: bf16 QS/KIN + register-transposed KINt/Vt + BC  (u dead after)
    gla_prep<<<dim3(B_*H_*NC_), blk, 0, stream>>>(ub, BC, QSb, KINb, KINtb, Vtb);
    // 3) per-chunk summaries McT[e][d] (MFMA, bf16 out) into old u region
    gla_chunk_mm<<<dim3(B_*H_*NC_), blk, 0, stream>>>(Vtb, KINtb, McTb);
    // 4) inter-chunk scan -> bf16 start states
    gla_scan_chunks<<<dim3((B_*H_*D_*D_)/256), blk, 0, stream>>>(McTb, BC, Sb16);
    // 5) per-chunk outputs (MFMA)
    gla_output<<<dim3(B_*H_*NC_), blk, 0, stream>>>(QSb, KINb, Vtb, Sb16, Opre);
    // 6) G1 = x @ W_g1^T  (bf16 out)
    gemm_bf16<true><<<dim3(1, M/128), blk, 0, stream>>>(xb, W_g1b, G1b, M, D_, E_);
    // 7) G2 = G1 @ W_g2^T (bf16 out, over dead QSb)
    gemm_bf16<true><<<dim3(E_/128, M/128), blk, 0, stream>>>(G1b, W_g2b, G2b, M, E_, D_);
    // 8) gate + layernorm -> bf16
    gate_ln_bf16<<<dim3(M), blk, 0, stream>>>(Opre, G2b, lnw, ObF);
    // 9) out = LN(o) @ W_out^T
    gemm_bf16<false><<<dim3(E_/128, M/128), blk, 0, stream>>>(ObF, W_outb, out, M, E_, E_);
}

// Round 7
// 215.002 us; speedup vs baseline: 5.5172x; 1.2159x over previous
//
#include <hip/hip_runtime.h>
#include <cmath>

#define B_ 2
#define N_ 4096
#define E_ 1024
#define D_ 128
#define H_ 8
#define CHUNK 64
#define NC_ (N_/CHUNK)   // 64

__device__ __forceinline__ float sigmoidf_(float x){ return 1.f/(1.f + __expf(-x)); }

__device__ __forceinline__ unsigned short f2bf(float f){
    unsigned u = __float_as_uint(f);
    u += 0x7FFFu + ((u >> 16) & 1u);      // round-to-nearest-even
    return (unsigned short)(u >> 16);
}
__device__ __forceinline__ float bf2f(unsigned short s){
    return __uint_as_float(((unsigned)s) << 16);
}
// single-instruction f32->bf16 (v_cvt_pk_bf16_f32 via scalar cast)
__device__ __forceinline__ unsigned short f2bf_fast(float f){
    __bf16 h = (__bf16)f;
    return __builtin_bit_cast(unsigned short, h);
}

typedef __attribute__((ext_vector_type(8))) __bf16 bf16x8;
typedef __attribute__((ext_vector_type(4))) float  f32x4;
typedef __attribute__((address_space(3))) unsigned int as3_u32;
typedef __attribute__((address_space(1))) unsigned int as1_u32;

__device__ __forceinline__ void gload_lds16(const void* g, void* l){
    __builtin_amdgcn_global_load_lds((as1_u32*)g, (as3_u32*)l, 16, 0, 0);
}

// fragment load from LDS tile with 256B rows (128 bf16/row), XOR-swizzled
__device__ __forceinline__ bf16x8 ldsfrag256(const unsigned short* Lp, int row, int kg){
    return *reinterpret_cast<const bf16x8*>(&Lp[row*128 + ((kg ^ (row&7))<<3)]);
}
// fragment load from LDS tile with 128B rows (64 bf16/row)
__device__ __forceinline__ bf16x8 ldsfrag128(const unsigned short* Lp, int row, int kg){
    return *reinterpret_cast<const bf16x8*>(&Lp[row*64 + ((kg ^ (row&7))<<3)]);
}

// ---------------------------------------------------------------------------
// bf16 MFMA GEMM: C[M,N] = A[M,K] @ Bw[N,K]^T.  128x128 tile, BK=64, 4 waves.
// + T1 bijective XCD swizzle (all grids have nwg % 8 == 0).
// ---------------------------------------------------------------------------
template<bool OUT_BF16>
__global__ __launch_bounds__(256) void gemm_bf16(
    const unsigned short* __restrict__ A,
    const unsigned short* __restrict__ Bw,
    void* __restrict__ Cout, int M, int N, int K)
{
    __shared__ unsigned short As[128*64];
    __shared__ unsigned short Bs[128*64];
    const int tid  = threadIdx.x;
    const int wave = tid >> 6;
    const int lane = tid & 63;
    const int gx = gridDim.x;
    const int nwg = gx * gridDim.y;
    int bid = blockIdx.y*gx + blockIdx.x;
    bid = (bid & 7)*(nwg >> 3) + (bid >> 3);
    const int m0 = (bid / gx) * 128, n0 = (bid % gx) * 128;
    const int wr = (wave >> 1) * 64;
    const int wc = (wave & 1) * 64;
    const int l15 = lane & 15, l4 = lane >> 4;
    const int p = l15 & 7;

    f32x4 acc[4][4];
#pragma unroll
    for (int i=0;i<4;i++)
#pragma unroll
        for (int j=0;j<4;j++)
#pragma unroll
            for (int q=0;q<4;q++) acc[i][j][q]=0.f;

    const int srow = wave*32 + (lane>>3);
    const int sgrp = lane & 7;

    for (int k0=0; k0<K; k0+=64){
        if (k0) __syncthreads();
#pragma unroll
        for (int i=0;i<4;i++){
            const int r  = srow + 8*i;
            const int cg = sgrp ^ (r & 7);
            gload_lds16(A  + (size_t)(m0 + r)*K + k0 + cg*8, &As[(wave*32 + 8*i)*64]);
            gload_lds16(Bw + (size_t)(n0 + r)*K + k0 + cg*8, &Bs[(wave*32 + 8*i)*64]);
        }
        __syncthreads();
#pragma unroll
        for (int ks=0; ks<2; ks++){
            bf16x8 av[4], bv[4];
            const int tA = (((ks<<2) | l4) ^ p) << 3;
#pragma unroll
            for (int f=0; f<4; f++){
                const int rowA = wr + f*16 + l15;
                const int rowB = wc + f*16 + l15;
                av[f] = *reinterpret_cast<const bf16x8*>(&As[(rowA<<6) + tA]);
                bv[f] = *reinterpret_cast<const bf16x8*>(&Bs[(rowB<<6) + tA]);
            }
#pragma unroll
            for (int fm=0; fm<4; fm++)
#pragma unroll
                for (int fn=0; fn<4; fn++)
                    acc[fm][fn] = __builtin_amdgcn_mfma_f32_16x16x32_bf16(
                        av[fm], bv[fn], acc[fm][fn], 0, 0, 0);
        }
    }
    const int crow0 = m0 + wr + l4*4;
    const int ccol0 = n0 + wc + l15;
    if (!OUT_BF16){
        float* C = (float*)Cout;
#pragma unroll
        for (int fm=0; fm<4; fm++)
#pragma unroll
            for (int fn=0; fn<4; fn++)
#pragma unroll
                for (int j=0;j<4;j++)
                    C[(size_t)(crow0 + fm*16 + j)*N + ccol0 + fn*16] = acc[fm][fn][j];
    } else {
        unsigned short* C = (unsigned short*)Cout;
#pragma unroll
        for (int fm=0; fm<4; fm++)
#pragma unroll
            for (int fn=0; fn<4; fn++)
#pragma unroll
                for (int j=0;j<4;j++)
                    C[(size_t)(crow0 + fm*16 + j)*N + ccol0 + fn*16] = f2bf(acc[fm][fn][j]);
    }
}

// ---------------------------------------------------------------------------
__global__ __launch_bounds__(256) void cast_bf16(
    const float* __restrict__ in, unsigned short* __restrict__ out, int n4)
{
    for (int i = blockIdx.x*256 + threadIdx.x; i < n4; i += gridDim.x*256){
        const float4 v = reinterpret_cast<const float4*>(in)[i];
        ushort4 o;
        o.x = f2bf(v.x); o.y = f2bf(v.y); o.z = f2bf(v.z); o.w = f2bf(v.w);
        reinterpret_cast<ushort4*>(out)[i] = o;
    }
}

// ---------------------------------------------------------------------------
// Prep v4: u bf16. 512 threads = (d 0..127) x (t-quarter 0..3, 16 steps each).
// Fast transcendentals: logsigmoid = min(lg,0) - log(1+e^{-|lg|}) via v_log;
// one exp(Bc) + rcp replaces three exps; single-op bf16 converts.
// Emits bf16 QS/KIN (row-major), KINt/Vt (transposed from regs), EBC=exp(BC).
// ---------------------------------------------------------------------------
__global__ __launch_bounds__(512) void gla_prep(
    const unsigned short* __restrict__ u, float* __restrict__ EBC,
    unsigned short* __restrict__ QSb, unsigned short* __restrict__ KINb,
    unsigned short* __restrict__ KINtb, unsigned short* __restrict__ Vtb)
{
    __shared__ float tot[4*128];
    const int bid = blockIdx.x;               // (b*H+h)*NC + c
    const int c  = bid % NC_;
    const int hh = (bid / NC_) % H_;
    const int b  = bid / (NC_*H_);
    const int d  = threadIdx.x & 127;
    const int qd = threadIdx.x >> 7;          // t-quarter (wave-uniform)
    const int t0 = qd*16;
    const size_t urow0 = ((size_t)b*N_ + (size_t)c*CHUNK)*(3*E_) + (size_t)hh*D_ + d;

    // preload all 48 values (fits in registers now)
    float bl[16], qv[16], vv[16];
#pragma unroll
    for (int i=0;i<16;i++)
        bl[i] = bf2f(u[urow0 + (size_t)(t0+i)*(3*E_) + 2*E_]);   // lg
#pragma unroll
    for (int i=0;i<16;i++)
        qv[i] = bf2f(u[urow0 + (size_t)(t0+i)*(3*E_) + E_]);     // q
#pragma unroll
    for (int i=0;i<16;i++)
        vv[i] = bf2f(u[urow0 + (size_t)(t0+i)*(3*E_)]);          // v

    // phase 1: local prefix of logsigmoid in registers
    float acc = 0.f;
#pragma unroll
    for (int i=0;i<16;i++){
        const float lg = bl[i];
        const float e  = __expf(-fabsf(lg));
        const float g  = fminf(lg, 0.f) - __logf(1.f + e);
        acc += g;
        bl[i] = acc;
    }
    tot[qd*128 + d] = acc;
    __syncthreads();
    const float s0 = tot[d], s1 = tot[128+d], s2 = tot[256+d], s3 = tot[384+d];
    const float off = (qd>0 ? s0 : 0.f) + (qd>1 ? s1 : 0.f) + (qd>2 ? s2 : 0.f);
    const float bcv = s0 + s1 + s2 + s3;
    const float ebc = __expf(bcv);
    if (threadIdx.x < 128) EBC[(size_t)bid*D_ + d] = ebc;

    // phase 2: compute + store
    unsigned kin_pk[8], v_pk[8];
    float prev = 0.f;
    const size_t obase = (size_t)bid*CHUNK*D_;
#pragma unroll
    for (int i=0;i<16;i++){
        const int t = t0 + i;
        const float Bl = bl[i];
        const float g  = Bl - prev;  prev = Bl;        // local diff (off cancels)
        const float Bc = Bl + off;                     // <= 0
        const float kk = 1.f - __expf(g);              // 1 - sigmoid(lg)
        const float eB = __expf(Bc);
        const float q  = qv[i];
        const float es = __expf(-q);
        const float silu = q * __builtin_amdgcn_rcpf(1.f + es);
        const float qs  = silu * eB;
        const float kin = kk * __builtin_amdgcn_rcpf(eB);   // kk * e^{-Bc}
        QSb [obase + (size_t)t*D_ + d] = f2bf_fast(qs);
        KINb[obase + (size_t)t*D_ + d] = f2bf_fast(kin);
        const unsigned kb = f2bf_fast(kin * ebc);           // kk * e^{bcv-Bc} <= 1
        const unsigned vb = f2bf_fast(vv[i]);
        if (i & 1){ kin_pk[i>>1] |= kb<<16; v_pk[i>>1] |= vb<<16; }
        else      { kin_pk[i>>1]  = kb;     v_pk[i>>1]  = vb;     }
    }
    const size_t tbase = (size_t)bid*D_*CHUNK + (size_t)d*CHUNK + t0;
#pragma unroll
    for (int j=0;j<2;j++){
        uint4 kq, vq;
        kq.x=kin_pk[4*j]; kq.y=kin_pk[4*j+1]; kq.z=kin_pk[4*j+2]; kq.w=kin_pk[4*j+3];
        vq.x=v_pk[4*j];   vq.y=v_pk[4*j+1];   vq.z=v_pk[4*j+2];   vq.w=v_pk[4*j+3];
        *reinterpret_cast<uint4*>(&KINtb[tbase + j*8]) = kq;
        *reinterpret_cast<uint4*>(&Vtb  [tbase + j*8]) = vq;
    }
}

// ---------------------------------------------------------------------------
// Batched chunk summary (MFMA): McT[bid][e][d] = sum_s Vt[e,s]*KINt[d,s]
// ---------------------------------------------------------------------------
__global__ __launch_bounds__(256) void gla_chunk_mm(
    const unsigned short* __restrict__ Vtb,
    const unsigned short* __restrict__ KINtb,
    unsigned short* __restrict__ McTb)
{
    __shared__ unsigned short As[128*64];
    __shared__ unsigned short Bs[128*64];
    const int bid = blockIdx.x;
    const int tid = threadIdx.x;
    const int w = tid >> 6, lane = tid & 63;
    const int l15 = lane & 15, l4 = lane >> 4;
    const int wr = (w >> 1) * 64, wc = (w & 1) * 64;
    const unsigned short* A  = Vtb   + (size_t)bid*128*64;
    const unsigned short* Bp = KINtb + (size_t)bid*128*64;

    f32x4 acc[4][4];
#pragma unroll
    for (int i=0;i<4;i++)
#pragma unroll
        for (int j=0;j<4;j++)
#pragma unroll
            for (int q=0;q<4;q++) acc[i][j][q]=0.f;

#pragma unroll
    for (int i=0;i<4;i++){
        const int r  = w*32 + i*8 + (lane>>3);
        const int gs = (lane&7) ^ (r&7);
        gload_lds16(A  + (size_t)r*64 + gs*8, &As[(w*32+i*8)*64]);
        gload_lds16(Bp + (size_t)r*64 + gs*8, &Bs[(w*32+i*8)*64]);
    }
    __syncthreads();
#pragma unroll
    for (int ks=0; ks<2; ks++){
        bf16x8 av[4], bv[4];
#pragma unroll
        for (int f=0; f<4; f++){
            av[f] = ldsfrag128(As, wr + f*16 + l15, ks*4 + l4);
            bv[f] = ldsfrag128(Bs, wc + f*16 + l15, ks*4 + l4);
        }
#pragma unroll
        for (int fm=0; fm<4; fm++)
#pragma unroll
            for (int fn=0; fn<4; fn++)
                acc[fm][fn] = __builtin_amdgcn_mfma_f32_16x16x32_bf16(
                    av[fm], bv[fn], acc[fm][fn], 0, 0, 0);
    }
    unsigned short* C = McTb + (size_t)bid*128*128;
#pragma unroll
    for (int fm=0; fm<4; fm++)
#pragma unroll
        for (int fn=0; fn<4; fn++)
#pragma unroll
            for (int j=0;j<4;j++)
                C[(size_t)(wr + fm*16 + l4*4 + j)*128 + wc + fn*16 + l15] = f2bf(acc[fm][fn][j]);
}

// ---------------------------------------------------------------------------
// Inter-chunk scan over bf16 McT[e][d]; dec pre-exponentiated (EBC).
// ---------------------------------------------------------------------------
__global__ __launch_bounds__(256) void gla_scan_chunks(
    const unsigned short* __restrict__ McTb, const float* __restrict__ EBC,
    unsigned short* __restrict__ Sb16)
{
    const size_t F = (size_t)blockIdx.x*256 + threadIdx.x;   // < B*H*D*D
    const int bh = (int)(F >> 14);
    const int rem = (int)(F & 16383);
    const int d = rem & 127;
    float S = 0.f;
    for (int c=0;c<NC_;c++){
        const size_t idx = (((size_t)bh*NC_ + c) << 14) + rem;
        const float m = bf2f(McTb[idx]);
        const float dec = EBC[((size_t)bh*NC_ + c)*D_ + d];
        Sb16[idx] = f2bf(S);
        S = dec*S + m;
    }
}

// ---------------------------------------------------------------------------
// Output (MFMA): per (b,h,chunk):
//   A[t,s] = causal(QS @ KIN^T);  O = A @ Vt^T + QS @ S^T  -> Opre [B,N,E] f32
// ---------------------------------------------------------------------------
__global__ __launch_bounds__(256) void gla_output(
    const unsigned short* __restrict__ QSb,
    const unsigned short* __restrict__ KINb,
    const unsigned short* __restrict__ Vtb,
    const unsigned short* __restrict__ Sb,
    float* __restrict__ Opre)
{
    __shared__ unsigned short QS_l[64*128];
    __shared__ unsigned short KA_l[64*128];   // KIN; first 8KB reused for A
    __shared__ unsigned short Vt_l[128*64];
    __shared__ unsigned short S_l [128*128];
    const int bid = blockIdx.x;
    const int c = bid % NC_;
    const int h = (bid / NC_) % H_;
    const int b = bid / (NC_*H_);
    const int tid = threadIdx.x;
    const int w = tid >> 6, lane = tid & 63;
    const int l15 = lane & 15, l4 = lane >> 4;

    {   // ---- stage (pre-swizzled sources, linear LDS dest) ----
        const unsigned short* q = QSb + (size_t)bid*64*128;
        const unsigned short* k = KINb + (size_t)bid*64*128;
        const unsigned short* v = Vtb + (size_t)bid*128*64;
        const unsigned short* s = Sb  + (size_t)bid*128*128;
#pragma unroll
        for (int i=0;i<4;i++){
            const int r  = w*16 + i*4 + (lane>>4);
            const int gs = (lane&15) ^ (r&7);
            gload_lds16(q + (size_t)r*128 + gs*8, &QS_l[(w*16+i*4)*128]);
            gload_lds16(k + (size_t)r*128 + gs*8, &KA_l[(w*16+i*4)*128]);
        }
#pragma unroll
        for (int i=0;i<4;i++){
            const int r  = w*32 + i*8 + (lane>>3);
            const int gs = (lane&7) ^ (r&7);
            gload_lds16(v + (size_t)r*64 + gs*8, &Vt_l[(w*32+i*8)*64]);
        }
#pragma unroll
        for (int i=0;i<8;i++){
            const int r  = w*32 + i*4 + (lane>>4);
            const int gs = (lane&15) ^ (r&7);
            gload_lds16(s + (size_t)r*128 + gs*8, &S_l[(w*32+i*4)*128]);
        }
    }
    __syncthreads();

    // ---- phase A: A[t, w*16 + l15] ----
    f32x4 accA[4];
#pragma unroll
    for (int i=0;i<4;i++)
#pragma unroll
        for (int q=0;q<4;q++) accA[i][q]=0.f;
    const int srow = w*16 + l15;
#pragma unroll
    for (int ks=0; ks<4; ks++){
        const bf16x8 bv = ldsfrag256(KA_l, srow, ks*4 + l4);
#pragma unroll
        for (int ft=0; ft<4; ft++){
            const bf16x8 av = ldsfrag256(QS_l, ft*16 + l15, ks*4 + l4);
            accA[ft] = __builtin_amdgcn_mfma_f32_16x16x32_bf16(av, bv, accA[ft], 0,0,0);
        }
    }
    __syncthreads();            // all KIN reads done before A overwrite
#pragma unroll
    for (int ft=0; ft<4; ft++)
#pragma unroll
        for (int j=0;j<4;j++){
            const int t = ft*16 + l4*4 + j;
            const int s = w*16 + l15;
            const float vA = (t >= s) ? accA[ft][j] : 0.f;
            KA_l[t*64 + (((s>>3) ^ (t&7))<<3) + (s&7)] = f2bf(vA);
        }
    __syncthreads();

    // ---- phase B: O[t, e-slab w] = A @ Vt^T + QS @ S^T ----
    f32x4 acc[4][2];
#pragma unroll
    for (int i=0;i<4;i++)
#pragma unroll
        for (int j=0;j<2;j++)
#pragma unroll
            for (int q=0;q<4;q++) acc[i][j][q]=0.f;
#pragma unroll
    for (int ks=0; ks<2; ks++){                 // O1: K = s = 64
        bf16x8 bv[2];
        bv[0] = ldsfrag128(Vt_l, w*32 +      l15, ks*4 + l4);
        bv[1] = ldsfrag128(Vt_l, w*32 + 16 + l15, ks*4 + l4);
#pragma unroll
        for (int ft=0; ft<4; ft++){
            const bf16x8 av = ldsfrag128(KA_l, ft*16 + l15, ks*4 + l4);
            acc[ft][0] = __builtin_amdgcn_mfma_f32_16x16x32_bf16(av, bv[0], acc[ft][0], 0,0,0);
            acc[ft][1] = __builtin_amdgcn_mfma_f32_16x16x32_bf16(av, bv[1], acc[ft][1], 0,0,0);
        }
    }
#pragma unroll
    for (int ks=0; ks<4; ks++){                 // O2: K = d = 128
        bf16x8 bv[2];
        bv[0] = ldsfrag256(S_l, w*32 +      l15, ks*4 + l4);
        bv[1] = ldsfrag256(S_l, w*32 + 16 + l15, ks*4 + l4);
#pragma unroll
        for (int ft=0; ft<4; ft++){
            const bf16x8 av = ldsfrag256(QS_l, ft*16 + l15, ks*4 + l4);
            acc[ft][0] = __builtin_amdgcn_mfma_f32_16x16x32_bf16(av, bv[0], acc[ft][0], 0,0,0);
            acc[ft][1] = __builtin_amdgcn_mfma_f32_16x16x32_bf16(av, bv[1], acc[ft][1], 0,0,0);
        }
    }
    const size_t rowbase = (size_t)b*N_ + (size_t)c*CHUNK;
#pragma unroll
    for (int ft=0; ft<4; ft++)
#pragma unroll
        for (int fe=0; fe<2; fe++)
#pragma unroll
            for (int j=0;j<4;j++){
                const int t = ft*16 + l4*4 + j;
                const int e = w*32 + fe*16 + l15;
                Opre[(rowbase + t)*E_ + h*D_ + e] = acc[ft][fe][j];
            }
}

// ---------------------------------------------------------------------------
// Gate (sigmoid of bf16 low-rank proj) + LayerNorm -> bf16
// ---------------------------------------------------------------------------
__global__ __launch_bounds__(256) void gate_ln_bf16(
    const float* __restrict__ O, const unsigned short* __restrict__ G2,
    const float* __restrict__ lnw, unsigned short* __restrict__ Ob)
{
    const int row = blockIdx.x;
    const int tid = threadIdx.x;
    const size_t off = (size_t)row*E_ + tid*4;
    float4 o = *reinterpret_cast<const float4*>(&O[off]);
    const ushort4 gu = *reinterpret_cast<const ushort4*>(&G2[off]);
    o.x *= sigmoidf_(bf2f(gu.x)); o.y *= sigmoidf_(bf2f(gu.y));
    o.z *= sigmoidf_(bf2f(gu.z)); o.w *= sigmoidf_(bf2f(gu.w));
    float s1 = o.x+o.y+o.z+o.w;
    float s2 = o.x*o.x + o.y*o.y + o.z*o.z + o.w*o.w;
#pragma unroll
    for (int sh=32; sh>0; sh>>=1){
        s1 += __shfl_down(s1, sh);
        s2 += __shfl_down(s2, sh);
    }
    __shared__ float r1[4], r2[4];
    const int wid = tid >> 6;
    if ((tid & 63)==0){ r1[wid]=s1; r2[wid]=s2; }
    __syncthreads();
    s1 = r1[0]+r1[1]+r1[2]+r1[3];
    s2 = r2[0]+r2[1]+r2[2]+r2[3];
    const float mean = s1 * (1.f/E_);
    const float var  = s2 * (1.f/E_) - mean*mean;
    const float rs   = rsqrtf(var + 1e-5f);
    const float4 w = *reinterpret_cast<const float4*>(&lnw[tid*4]);
    ushort4 r;
    r.x = f2bf((o.x-mean)*rs*w.x); r.y = f2bf((o.y-mean)*rs*w.y);
    r.z = f2bf((o.z-mean)*rs*w.z); r.w = f2bf((o.w-mean)*rs*w.w);
    *reinterpret_cast<ushort4*>(&Ob[off]) = r;
}

// ---------------------------------------------------------------------------
extern "C" void kernel_launch(void* const* d_in, const int* in_sizes, int n_in,
                              void* d_out, int out_size, void* d_ws, size_t ws_size,
                              hipStream_t stream)
{
    const float* x     = (const float*)d_in[0];
    const float* W_in  = (const float*)d_in[1];
    const float* W_out = (const float*)d_in[2];
    const float* W_g1  = (const float*)d_in[3];
    const float* W_g2  = (const float*)d_in[4];
    const float* lnw   = (const float*)d_in[5];
    float* out = (float*)d_out;
    char* ws = (char*)d_ws;

    // workspace layout (bytes); total 246,415,360 (< 256 MiB)
    unsigned short* ub     = (unsigned short*)(ws);             // [B,N,3E] bf16 (dead after prep); reused:
    unsigned short* McTb   = (unsigned short*)(ws);             //   [B,H,NC,D,D] bf16 33,554,432
    unsigned short* Sb16   = (unsigned short*)(ws + 33554432);  //   [B,H,NC,D,D] bf16 33,554,432
    float*          EBC    = (float*)(ws + 100663296);          //       524,288
    unsigned short* QSb    = (unsigned short*)(ws + 101187584); //    16,777,216
    unsigned short* KINb   = (unsigned short*)(ws + 117964800); //    16,777,216
    unsigned short* KINtb  = (unsigned short*)(ws + 134742016); //    16,777,216
    unsigned short* Vtb    = (unsigned short*)(ws + 151519232); //    16,777,216
    float*          Opre   = (float*)(ws + 168296448);          //    33,554,432
    unsigned short* xb     = (unsigned short*)(ws + 201850880); //    16,777,216
    unsigned short* W_inb  = (unsigned short*)(ws + 218628096); //     6,291,456
    unsigned short* W_outb = (unsigned short*)(ws + 224919552); //     2,097,152
    unsigned short* W_g1b  = (unsigned short*)(ws + 227016704); //       262,144
    unsigned short* W_g2b  = (unsigned short*)(ws + 227278848); //       262,144
    unsigned short* G1b    = (unsigned short*)(ws + 227540992); //     2,097,152
    unsigned short* ObF    = (unsigned short*)(ws + 229638144); //    16,777,216
    unsigned short* G2b    = QSb;   // reuse QSb (dead after gla_output)

    const int M = B_*N_;     // 8192
    dim3 blk(256);

    // casts to bf16
    cast_bf16<<<2048, blk, 0, stream>>>(x,     xb,     (B_*N_*E_)/4);
    cast_bf16<<<2048, blk, 0, stream>>>(W_in,  W_inb,  (3*E_*E_)/4);
    cast_bf16<<<1024, blk, 0, stream>>>(W_out, W_outb, (E_*E_)/4);
    cast_bf16<<<128,  blk, 0, stream>>>(W_g1,  W_g1b,  (D_*E_)/4);
    cast_bf16<<<128,  blk, 0, stream>>>(W_g2,  W_g2b,  (E_*D_)/4);

    // 1) u = x @ W_in^T  (bf16 out)
    gemm_bf16<true><<<dim3(3*E_/128, M/128), blk, 0, stream>>>(xb, W_inb, ub, M, 3*E_, E_);
    // 2) prep: bf16 QS/KIN + register-transposed KINt/Vt + EBC  (u dead after)
    gla_prep<<<dim3(B_*H_*NC_), dim3(512), 0, stream>>>(ub, EBC, QSb, KINb, KINtb, Vtb);
    // 3) per-chunk summaries McT[e][d] (MFMA, bf16 out) into old u region
    gla_chunk_mm<<<dim3(B_*H_*NC_), blk, 0, stream>>>(Vtb, KINtb, McTb);
    // 4) inter-chunk scan -> bf16 start states
    gla_scan_chunks<<<dim3((B_*H_*D_*D_)/256), blk, 0, stream>>>(McTb, EBC, Sb16);
    // 5) per-chunk outputs (MFMA)
    gla_output<<<dim3(B_*H_*NC_), blk, 0, stream>>>(QSb, KINb, Vtb, Sb16, Opre);
    // 6) G1 = x @ W_g1^T  (bf16 out)
    gemm_bf16<true><<<dim3(1, M/128), blk, 0, stream>>>(xb, W_g1b, G1b, M, D_, E_);
    // 7) G2 = G1 @ W_g2^T (bf16 out, over dead QSb)
    gemm_bf16<true><<<dim3(E_/128, M/128), blk, 0, stream>>>(G1b, W_g2b, G2b, M, E_, D_);
    // 8) gate + layernorm -> bf16
    gate_ln_bf16<<<dim3(M), blk, 0, stream>>>(Opre, G2b, lnw, ObF);
    // 9) out = LN(o) @ W_out^T
    gemm_bf16<false><<<dim3(E_/128, M/128), blk, 0, stream>>>(ObF, W_outb, out, M, E_, E_);
}